// Round 9
// baseline (251.819 us; speedup 1.0000x reference)
//
#include <hip/hip_runtime.h>
#include <hip/hip_bf16.h>
#include <hip/hip_fp16.h>
#include <math.h>

// ---------------------------------------------------------------------------
// DynamicGCN: 3x (GCNConv -> ReLU -> *gate)
// R1: multi-block scan, hist fused into convert, dinv folded into scan C.
// R2: split-bf16 MFMA GEMM, W pre-swizzled into B-fragment order.
// R10: agg CSR padded (tail-free loop); self-edge folded into agg.
// R11: Wf staged per-kc into LDS (double-buffered); X loads global->reg;
//     agg half-wave/node, edge-meta software-pipelined.
// R12: bucket is throughput-bound on scattered partial-line HBM writes;
//     occupancy is NOT the limiter.
// R13: prep fusion KEPT; heterogeneous block-split fusion REVERTED.
// R14/R16: 4B bucket scatter + expand_kernel (edges8 = (src, dinv[src]),
//     pads (0,0)) -- norm recompute OFF agg's critical path.
// R17: layers 1/2 fp16 single-plane X + fp16 hi/lo-split W
//     (mfma_f32_16x16x32_f16, 2 MFMAs/frag). absmax unchanged (0.00195).
// R18: agg was round-latency-bound (VALU 33%, occ 65%, ~2 serial gather
//     rounds per avg node). CSR capacity cap4 -> cap8; agg unrolled 8-deep
//     (8 gathers in flight/half-wave, next-round meta prefetched). Pads are
//     zero-norm => no predication (R8's 8-deep failed on predicate VALU).
//     Avg serial rounds 2.0 -> 1.2.
// ---------------------------------------------------------------------------

#define D 128   // feature dim (D_IN == HID == 128)

typedef __attribute__((ext_vector_type(8))) short short8;
typedef __attribute__((ext_vector_type(8))) _Float16 half8;
typedef __attribute__((ext_vector_type(4))) float floatx4;

__device__ __forceinline__ unsigned bf16_rne(float x) {
    unsigned u = __float_as_uint(x);
    return (u + 0x7FFFu + ((u >> 16) & 1u)) >> 16;
}

__device__ __forceinline__ void gload_lds16(const void* g, void* l) {
    __builtin_amdgcn_global_load_lds(
        (const __attribute__((address_space(1))) unsigned int*)g,
        (__attribute__((address_space(3))) unsigned int*)l, 16, 0, 0);
}

__device__ __forceinline__ float h2f(unsigned short u) {
    return __half2float(__ushort_as_half(u));
}

// ---- prep: W swizzle (blocks 0..23) + gate MLP (24) + edge convert (25..) -
// Layer 0 fragments: bf16 hi/lo split. Layers 1/2: fp16 hi/lo split.
__global__ __launch_bounds__(256) void prep_kernel(
    const int* __restrict__ w, int* __restrict__ src32,
    int* __restrict__ dst32, int* __restrict__ counts, int E,
    const float* __restrict__ W0, const float* __restrict__ W1,
    const float* __restrict__ W2, short8* __restrict__ Wf_hi,
    short8* __restrict__ Wf_lo,
    const float* __restrict__ t, const float* __restrict__ Wg1,
    const float* __restrict__ bg1, const float* __restrict__ Wg2,
    const float* __restrict__ bg2, float* __restrict__ gate)
{
    int b = blockIdx.x;
    if (b < 24) {
        int f = b * 256 + threadIdx.x;   // 0..6143
        int layer = f >> 11;
        int fi = f & 2047;
        int lane = fi & 63;
        int tt = fi >> 6;                // kc*8 + n
        int kc = tt >> 3, n = tt & 7;
        const float* W = (layer == 0) ? W0 : (layer == 1) ? W1 : W2;
        int krow = kc * 32 + (lane >> 4) * 8;
        int col = n * 16 + (lane & 15);
        short8 hv, lv;
        if (layer == 0) {
            #pragma unroll
            for (int j = 0; j < 8; j++) {
                float x = W[(size_t)(krow + j) * D + col];
                unsigned hb = bf16_rne(x);
                float hf = __uint_as_float(hb << 16);
                unsigned lb = bf16_rne(x - hf);
                hv[j] = (short)hb;
                lv[j] = (short)lb;
            }
        } else {
            #pragma unroll
            for (int j = 0; j < 8; j++) {
                float x = W[(size_t)(krow + j) * D + col];
                __half hh = __float2half(x);
                float hf = __half2float(hh);
                __half ll = __float2half(x - hf);
                hv[j] = (short)__half_as_ushort(hh);
                lv[j] = (short)__half_as_ushort(ll);
            }
        }
        Wf_hi[f] = hv;
        Wf_lo[f] = lv;
        return;
    }
    if (b == 24) {
        __shared__ float u[D];
        int j = threadIdx.x;
        if (j < D) {
            float tv = t[0];
            u[j] = tanhf(tv * Wg1[j] + bg1[j]);
        }
        __syncthreads();
        if (j < D) {
            float s = bg2[j];
            #pragma unroll 8
            for (int k = 0; k < D; k++) s += u[k] * Wg2[k * D + j];
            gate[j] = 1.0f / (1.0f + expf(-s));
        }
        return;
    }
    // ---- edge convert (int64 auto-detect) + fused degree histogram ----
    __shared__ int flag;
    if (threadIdx.x == 0) {
        int z = 0;
        for (int k = 0; k < 64; k++) z |= w[2 * k + 1];
        flag = (z == 0) ? 1 : 0;   // all odd words zero => int64 layout
    }
    __syncthreads();
    int i64 = flag;
    int e = (b - 25) * 256 + threadIdx.x;
    if (e >= E) return;
    int s = i64 ? w[2 * e] : w[e];                       // little-endian low word
    int d = i64 ? w[2 * (E + e)] : w[E + e];
    src32[e] = s;
    dst32[e] = d;
    atomicAdd(&counts[d], 1);
}

// ------------------- multi-block exclusive scan ----------------------------
// Scans CAPACITY = (counts[i]+7)&~7 (edges padded to x8 for the 8-deep agg;
// self-edge handled inside agg, NOT stored in CSR).
#define SCHUNK 1024
__device__ __forceinline__ int cap8(int c) { return (c + 7) & ~7; }

__global__ __launch_bounds__(256) void scan_partial_kernel(
    const int* __restrict__ counts, int* __restrict__ bsums, int N)
{
    int base = blockIdx.x * SCHUNK + threadIdx.x * 4;
    int s = 0;
    if (base + 3 < N) {
        int4 v = *(const int4*)(counts + base);
        s = cap8(v.x) + cap8(v.y) + cap8(v.z) + cap8(v.w);
    } else {
        for (int k = 0; k < 4; k++) if (base + k < N) s += cap8(counts[base + k]);
    }
    #pragma unroll
    for (int off = 1; off < 64; off <<= 1) s += __shfl_xor(s, off);
    __shared__ int wsum[4];
    int lane = threadIdx.x & 63, wid = threadIdx.x >> 6;
    if (lane == 0) wsum[wid] = s;
    __syncthreads();
    if (threadIdx.x == 0)
        bsums[blockIdx.x] = wsum[0] + wsum[1] + wsum[2] + wsum[3];
}

__global__ __launch_bounds__(1024) void scan_bsums_kernel(
    int* __restrict__ bsums, int* __restrict__ total_out, int B)
{
    int t = threadIdx.x;
    int v = (t < B) ? bsums[t] : 0;
    int lane = t & 63, wid = t >> 6;
    int s = v;
    #pragma unroll
    for (int off = 1; off < 64; off <<= 1) {
        int n = __shfl_up(s, off);
        if (lane >= off) s += n;
    }
    __shared__ int wsum[16], wpre[16];
    if (lane == 63) wsum[wid] = s;
    __syncthreads();
    if (t < 16) {
        int ws = wsum[t];
        #pragma unroll
        for (int off = 1; off < 16; off <<= 1) {
            int n = __shfl_up(ws, off);
            if (t >= off) ws += n;
        }
        wpre[t] = ws;
    }
    __syncthreads();
    int wex = wid ? wpre[wid - 1] : 0;
    if (t < B) bsums[t] = wex + (s - v);      // exclusive
    if (t == 0) *total_out = wpre[15];        // grand total -> offsets[N]
}

__global__ __launch_bounds__(256) void scan_final_kernel(
    const int* __restrict__ counts, const int* __restrict__ bsums,
    int* __restrict__ offsets, int* __restrict__ cursor,
    float* __restrict__ dinv, int N)
{
    int base = blockIdx.x * SCHUNK + threadIdx.x * 4;
    int c[4];
    float dd[4];
    bool full = (base + 3 < N);
    if (full) {
        int4 v = *(const int4*)(counts + base);
        c[0] = cap8(v.x); c[1] = cap8(v.y); c[2] = cap8(v.z); c[3] = cap8(v.w);
        dd[0] = rsqrtf((float)(v.x + 1)); dd[1] = rsqrtf((float)(v.y + 1));
        dd[2] = rsqrtf((float)(v.z + 1)); dd[3] = rsqrtf((float)(v.w + 1));
    } else {
        for (int k = 0; k < 4; k++) {
            int r = (base + k < N) ? counts[base + k] : 0;
            c[k] = (base + k < N) ? cap8(r) : 0;
            dd[k] = rsqrtf((float)(r + 1));
        }
    }
    int sum = c[0] + c[1] + c[2] + c[3];
    int lane = threadIdx.x & 63, wid = threadIdx.x >> 6;
    int s = sum;
    #pragma unroll
    for (int off = 1; off < 64; off <<= 1) {
        int n = __shfl_up(s, off);
        if (lane >= off) s += n;
    }
    __shared__ int wsum[4], wpre[4];
    if (lane == 63) wsum[wid] = s;
    __syncthreads();
    if (threadIdx.x == 0) {
        int a = 0;
        #pragma unroll
        for (int k = 0; k < 4; k++) { wpre[k] = a; a += wsum[k]; }
    }
    __syncthreads();
    int e0 = bsums[blockIdx.x] + wpre[wid] + (s - sum);
    int4 o = make_int4(e0, e0 + c[0], e0 + c[0] + c[1], e0 + c[0] + c[1] + c[2]);
    float4 dv = make_float4(dd[0], dd[1], dd[2], dd[3]);
    if (full) {
        *(int4*)(offsets + base) = o;
        *(int4*)(cursor + base) = o;
        *(float4*)(dinv + base) = dv;
    } else {
        int oo[4] = { o.x, o.y, o.z, o.w };
        for (int k = 0; k < 4; k++)
            if (base + k < N) {
                offsets[base + k] = oo[k];
                cursor[base + k] = oo[k];
                dinv[base + k] = dd[k];
            }
    }
}

// ---------- bucket edges by dst (CSR, 4B src-only payload) -----------------
__global__ __launch_bounds__(256) void bucket_kernel(
    const int* __restrict__ src32, const int* __restrict__ dst32,
    int* __restrict__ cursor, int* __restrict__ edges4, int E)
{
    int e = blockIdx.x * blockDim.x + threadIdx.x;
    if (e >= E) return;
    int s = src32[e];
    int d = dst32[e];
    int pos = atomicAdd(&cursor[d], 1);
    edges4[pos] = s;
}

// ---------- expand: edges4 -> edges8 = (src, dinv[src]); pads -> (0,0) -----
__global__ __launch_bounds__(256) void expand_kernel(
    const int* __restrict__ edges4, const float* __restrict__ dinv,
    int2* __restrict__ edges8, int cap)
{
    int i = blockIdx.x * blockDim.x + threadIdx.x;
    if (i >= cap) return;
    int s = edges4[i];
    int ss = (s < 0) ? 0 : s;
    float f = (s < 0) ? 0.f : dinv[ss];
    edges8[i] = make_int2(ss, __float_as_int(f));
}

// ----- cooperative Wf stage: 16KB (hi 8KB + lo 8KB) per kc into LDS --------
#define WSTAGE(kc_)                                                           \
    {                                                                         \
        short* wb_ = Wfs + (((kc_) & 1) ? 8192 : 0);                          \
        const short8* gh_ = Wf_hi + (size_t)(kc_) * 512;                      \
        const short8* gl_ = Wf_lo + (size_t)(kc_) * 512;                      \
        _Pragma("unroll")                                                     \
        for (int i_ = 0; i_ < 2; i_++) {                                      \
            int c_ = i_ * 256 + w * 64;                                       \
            gload_lds16(gh_ + c_ + lane, wb_ + c_ * 8);                       \
            gload_lds16(gl_ + c_ + lane, wb_ + 4096 + c_ * 8);                \
        }                                                                     \
    }

// ------------- bf16 split MFMA inner block (layer 0) -----------------------
#define MFMA_BLOCK(kc)                                                        \
    {                                                                         \
        const short* wb = Wfs + (((kc) & 1) ? 8192 : 0);                      \
        _Pragma("unroll")                                                     \
        for (int n = 0; n < 8; n++) {                                         \
            short8 bh = *(const short8*)(wb + (n * 64 + lane) * 8);           \
            short8 bl = *(const short8*)(wb + 4096 + (n * 64 + lane) * 8);    \
            acc[0][n] = __builtin_amdgcn_mfma_f32_16x16x32_bf16(ah0, bh, acc[0][n], 0, 0, 0); \
            acc[0][n] = __builtin_amdgcn_mfma_f32_16x16x32_bf16(ah0, bl, acc[0][n], 0, 0, 0); \
            acc[0][n] = __builtin_amdgcn_mfma_f32_16x16x32_bf16(al0, bh, acc[0][n], 0, 0, 0); \
            acc[1][n] = __builtin_amdgcn_mfma_f32_16x16x32_bf16(ah1, bh, acc[1][n], 0, 0, 0); \
            acc[1][n] = __builtin_amdgcn_mfma_f32_16x16x32_bf16(ah1, bl, acc[1][n], 0, 0, 0); \
            acc[1][n] = __builtin_amdgcn_mfma_f32_16x16x32_bf16(al1, bh, acc[1][n], 0, 0, 0); \
        }                                                                     \
    }

// ------------- fp16 split-W MFMA inner block (layers 1/2) ------------------
#define MFMA_BLOCK_F16(kc)                                                    \
    {                                                                         \
        const short* wb = Wfs + (((kc) & 1) ? 8192 : 0);                      \
        _Pragma("unroll")                                                     \
        for (int n = 0; n < 8; n++) {                                         \
            half8 bh = *(const half8*)(wb + (n * 64 + lane) * 8);             \
            half8 bl = *(const half8*)(wb + 4096 + (n * 64 + lane) * 8);      \
            acc[0][n] = __builtin_amdgcn_mfma_f32_16x16x32_f16(ah0, bh, acc[0][n], 0, 0, 0); \
            acc[0][n] = __builtin_amdgcn_mfma_f32_16x16x32_f16(ah0, bl, acc[0][n], 0, 0, 0); \
            acc[1][n] = __builtin_amdgcn_mfma_f32_16x16x32_f16(ah1, bh, acc[1][n], 0, 0, 0); \
            acc[1][n] = __builtin_amdgcn_mfma_f32_16x16x32_f16(ah1, bl, acc[1][n], 0, 0, 0); \
        }                                                                     \
    }

#define EPILOGUE()                                                            \
    _Pragma("unroll")                                                         \
    for (int rt = 0; rt < 2; rt++) {                                          \
        _Pragma("unroll")                                                     \
        for (int reg = 0; reg < 4; reg++) {                                   \
            int row = rowbase + rt * 16 + qd * 4 + reg;                       \
            if (row < M) {                                                    \
                unsigned short* hp = H16 + (size_t)row * D + m16;             \
                _Pragma("unroll")                                             \
                for (int n = 0; n < 8; n++)                                   \
                    hp[n * 16] = __half_as_ushort(__float2half(acc[rt][n][reg])); \
            }                                                                 \
        }                                                                     \
    }

// ------------- GEMM variant A: fp32 X input (layer 0 only) -----------------
#define GBM 128
__device__ __forceinline__ void cvt8(const float* f, short8& hi, short8& lo) {
    #pragma unroll
    for (int j = 0; j < 8; j++) {
        unsigned hb = bf16_rne(f[j]);
        float hf = __uint_as_float(hb << 16);
        unsigned lb = bf16_rne(f[j] - hf);
        hi[j] = (short)hb;
        lo[j] = (short)lb;
    }
}

__global__ __launch_bounds__(256) void gemm_f32_kernel(
    const float* __restrict__ X, const short8* __restrict__ Wf_hi,
    const short8* __restrict__ Wf_lo, unsigned short* __restrict__ H16, int M)
{
    __shared__ short Wfs[16384];   // 32KB: 2 bufs x (hi 8KB + lo 8KB)
    int tid = threadIdx.x;
    int w = tid >> 6, lane = tid & 63;
    int m16 = lane & 15, qd = lane >> 4;
    int rowbase = blockIdx.x * GBM + w * 32;

    int r0 = rowbase + m16;      if (r0 >= M) r0 = M - 1;
    int r1 = rowbase + m16 + 16; if (r1 >= M) r1 = M - 1;
    const float* xp0 = X + (size_t)r0 * D + qd * 8;
    const float* xp1 = X + (size_t)r1 * D + qd * 8;

    floatx4 acc[2][8];
    #pragma unroll
    for (int rt = 0; rt < 2; rt++)
        #pragma unroll
        for (int n = 0; n < 8; n++)
            acc[rt][n] = (floatx4)(0.f);

    #define LOADA(kc_, A0, A1)                                              \
        {                                                                   \
            *(float4*)(A0)     = *(const float4*)(xp0 + (kc_) * 32);        \
            *(float4*)(A0 + 4) = *(const float4*)(xp0 + (kc_) * 32 + 4);    \
            *(float4*)(A1)     = *(const float4*)(xp1 + (kc_) * 32);        \
            *(float4*)(A1 + 4) = *(const float4*)(xp1 + (kc_) * 32 + 4);    \
        }

    float a0c[8], a1c[8], a0n[8], a1n[8];
    WSTAGE(0)
    LOADA(0, a0c, a1c)

    #pragma unroll
    for (int kc = 0; kc < 4; kc++) {
        __syncthreads();     // drains vmcnt: Wf(kc) in LDS, A(kc) in regs
        if (kc < 3) {
            WSTAGE(kc + 1)
            LOADA(kc + 1, a0n, a1n)
        }
        short8 ah0, al0, ah1, al1;
        cvt8(a0c, ah0, al0);
        cvt8(a1c, ah1, al1);
        MFMA_BLOCK(kc)
        if (kc < 3) {
            #pragma unroll
            for (int z = 0; z < 8; z++) { a0c[z] = a0n[z]; a1c[z] = a1n[z]; }
        }
    }
    #undef LOADA
    EPILOGUE()
}

// ------ GEMM variant B: fp16 single-plane X input (layers 1,2) -------------
__global__ __launch_bounds__(256) void gemm_f16_kernel(
    const unsigned short* __restrict__ Xh,
    const short8* __restrict__ Wf_hi, const short8* __restrict__ Wf_lo,
    unsigned short* __restrict__ H16, int M)
{
    __shared__ short Wfs[16384];   // 32KB: 2 bufs x (hi 8KB + lo 8KB)
    int tid = threadIdx.x;
    int w = tid >> 6, lane = tid & 63;
    int m16 = lane & 15, qd = lane >> 4;
    int rowbase = blockIdx.x * GBM + w * 32;

    int r0 = rowbase + m16;      if (r0 >= M) r0 = M - 1;
    int r1 = rowbase + m16 + 16; if (r1 >= M) r1 = M - 1;
    const unsigned short* xh0 = Xh + (size_t)r0 * D + qd * 8;
    const unsigned short* xh1 = Xh + (size_t)r1 * D + qd * 8;

    floatx4 acc[2][8];
    #pragma unroll
    for (int rt = 0; rt < 2; rt++)
        #pragma unroll
        for (int n = 0; n < 8; n++)
            acc[rt][n] = (floatx4)(0.f);

    half8 ah0, ah1, nh0, nh1;
    WSTAGE(0)
    ah0 = *(const half8*)(xh0);
    ah1 = *(const half8*)(xh1);

    #pragma unroll
    for (int kc = 0; kc < 4; kc++) {
        __syncthreads();     // drains vmcnt: Wf(kc) in LDS, A(kc) in regs
        if (kc < 3) {
            WSTAGE(kc + 1)
            nh0 = *(const half8*)(xh0 + (kc + 1) * 32);
            nh1 = *(const half8*)(xh1 + (kc + 1) * 32);
        }
        MFMA_BLOCK_F16(kc)
        if (kc < 3) { ah0 = nh0; ah1 = nh1; }
    }
    EPILOGUE()
}

// ------- per-node aggregation: half-wave/node, tail-free, 8-deep -----------
// CSR capacity padded to x8 with (src=0, norm=0.0f) dummies: every round is
// 8 independent gathers in flight; next round's meta (4x int4) prefetched.
// Avg node (deg 6 -> cap 8) completes in ONE round. nv = npartial * dv.
__global__ __launch_bounds__(256) void agg_kernel(
    const unsigned short* __restrict__ H16, const int2* __restrict__ edges,
    const int* __restrict__ offsets, const float* __restrict__ dinv,
    const float* __restrict__ bias, const float* __restrict__ gate,
    float* __restrict__ outF, unsigned short* __restrict__ outH,
    int M, int writeF32)
{
    int t = threadIdx.x;
    int hw = t >> 5;                  // half-wave 0..7
    int l32 = t & 31;
    int node = blockIdx.x * 8 + hw;
    if (node >= M) return;

    int beg = offsets[node];
    int end = offsets[node + 1];
    float dv = dinv[node];
    const unsigned short* __restrict__ Hc = H16 + l32 * 4;
    // self row: issue load early, consume after the gather loop
    ushort4 us = *(const ushort4*)(Hc + (size_t)node * D);
    float4 acc = make_float4(0.f, 0.f, 0.f, 0.f);

    int4 p0 = make_int4(0, 0, 0, 0), p1 = p0, p2 = p0, p3 = p0;
    if (beg < end) {
        p0 = *(const int4*)(edges + beg);       // (s0,f0,s1,f1)
        p1 = *(const int4*)(edges + beg + 2);
        p2 = *(const int4*)(edges + beg + 4);
        p3 = *(const int4*)(edges + beg + 6);
    }
    for (int j = beg; j < end; j += 8) {
        int jn = j + 8;
        int jp = (jn < end) ? jn : beg;         // clamped: always valid
        int4 q0 = *(const int4*)(edges + jp);
        int4 q1 = *(const int4*)(edges + jp + 2);
        int4 q2 = *(const int4*)(edges + jp + 4);
        int4 q3 = *(const int4*)(edges + jp + 6);
        ushort4 u0 = *(const ushort4*)(Hc + (size_t)p0.x * D);
        ushort4 u1 = *(const ushort4*)(Hc + (size_t)p0.z * D);
        ushort4 u2 = *(const ushort4*)(Hc + (size_t)p1.x * D);
        ushort4 u3 = *(const ushort4*)(Hc + (size_t)p1.z * D);
        ushort4 u4 = *(const ushort4*)(Hc + (size_t)p2.x * D);
        ushort4 u5 = *(const ushort4*)(Hc + (size_t)p2.z * D);
        ushort4 u6 = *(const ushort4*)(Hc + (size_t)p3.x * D);
        ushort4 u7 = *(const ushort4*)(Hc + (size_t)p3.z * D);
        float n0 = __int_as_float(p0.y) * dv, n1 = __int_as_float(p0.w) * dv;
        float n2 = __int_as_float(p1.y) * dv, n3 = __int_as_float(p1.w) * dv;
        float n4 = __int_as_float(p2.y) * dv, n5 = __int_as_float(p2.w) * dv;
        float n6 = __int_as_float(p3.y) * dv, n7 = __int_as_float(p3.w) * dv;
        acc.x = fmaf(h2f(u3.x), n3, fmaf(h2f(u2.x), n2, fmaf(h2f(u1.x), n1, fmaf(h2f(u0.x), n0, acc.x))));
        acc.y = fmaf(h2f(u3.y), n3, fmaf(h2f(u2.y), n2, fmaf(h2f(u1.y), n1, fmaf(h2f(u0.y), n0, acc.y))));
        acc.z = fmaf(h2f(u3.z), n3, fmaf(h2f(u2.z), n2, fmaf(h2f(u1.z), n1, fmaf(h2f(u0.z), n0, acc.z))));
        acc.w = fmaf(h2f(u3.w), n3, fmaf(h2f(u2.w), n2, fmaf(h2f(u1.w), n1, fmaf(h2f(u0.w), n0, acc.w))));
        acc.x = fmaf(h2f(u7.x), n7, fmaf(h2f(u6.x), n6, fmaf(h2f(u5.x), n5, fmaf(h2f(u4.x), n4, acc.x))));
        acc.y = fmaf(h2f(u7.y), n7, fmaf(h2f(u6.y), n6, fmaf(h2f(u5.y), n5, fmaf(h2f(u4.y), n4, acc.y))));
        acc.z = fmaf(h2f(u7.z), n7, fmaf(h2f(u6.z), n6, fmaf(h2f(u5.z), n5, fmaf(h2f(u4.z), n4, acc.z))));
        acc.w = fmaf(h2f(u7.w), n7, fmaf(h2f(u6.w), n6, fmaf(h2f(u5.w), n5, fmaf(h2f(u4.w), n4, acc.w))));
        p0 = q0; p1 = q1; p2 = q2; p3 = q3;
    }

    // self-loop term: norm = dinv^2 = 1/deg (exact, matches reference)
    float nself = dv * dv;
    acc.x = fmaf(h2f(us.x), nself, acc.x);
    acc.y = fmaf(h2f(us.y), nself, acc.y);
    acc.z = fmaf(h2f(us.z), nself, acc.z);
    acc.w = fmaf(h2f(us.w), nself, acc.w);

    float4 bv = *(const float4*)(bias + l32 * 4);
    float4 gv = *(const float4*)(gate + l32 * 4);
    acc.x = fmaxf(acc.x + bv.x, 0.f) * gv.x;
    acc.y = fmaxf(acc.y + bv.y, 0.f) * gv.y;
    acc.z = fmaxf(acc.z + bv.z, 0.f) * gv.z;
    acc.w = fmaxf(acc.w + bv.w, 0.f) * gv.w;

    if (writeF32) {
        *(float4*)(outF + (size_t)node * D + l32 * 4) = acc;
    } else {
        ushort4 hs = make_ushort4(
            __half_as_ushort(__float2half(acc.x)),
            __half_as_ushort(__float2half(acc.y)),
            __half_as_ushort(__float2half(acc.z)),
            __half_as_ushort(__float2half(acc.w)));
        *(ushort4*)(outH + (size_t)node * D + l32 * 4) = hs;
    }
}

// ---------------------------------------------------------------------------
static inline size_t align_up(size_t v, size_t a) { return (v + a - 1) & ~(a - 1); }

extern "C" void kernel_launch(void* const* d_in, const int* in_sizes, int n_in,
                              void* d_out, int out_size, void* d_ws, size_t ws_size,
                              hipStream_t stream)
{
    const float* x   = (const float*)d_in[0];
    const int*   ei  = (const int*)d_in[1];   // int32 or int64 (auto-detected)
    const float* ts  = (const float*)d_in[2];
    const float* Wl[3] = { (const float*)d_in[3], (const float*)d_in[5], (const float*)d_in[7] };
    const float* bl[3] = { (const float*)d_in[4], (const float*)d_in[6], (const float*)d_in[8] };
    const float* Wg1 = (const float*)d_in[9];
    const float* bg1 = (const float*)d_in[10];
    const float* Wg2 = (const float*)d_in[11];
    const float* bg2 = (const float*)d_in[12];

    const int N = in_sizes[0] / D;      // 100000
    const int E = in_sizes[1] / 2;      // 600000
    const int NB = (N + SCHUNK - 1) / SCHUNK;   // scan blocks
    const size_t ECAP = (size_t)E + 7 * (size_t)N;  // x8-padded CSR worst case

    // workspace carve (all 256B aligned)
    char* p = (char*)d_ws;
    unsigned short* h16 = (unsigned short*)p; p += align_up((size_t)N * D * 2, 256);
    unsigned short* xh  = (unsigned short*)p; p += align_up((size_t)N * D * 2, 256);
    int* src32  = (int*)p;   p += align_up((size_t)E * 4, 256);
    int* dst32  = (int*)p;   p += align_up((size_t)E * 4, 256);
    int* counts = (int*)p;   p += align_up((size_t)N * 4, 256);
    float* dinv = (float*)p; p += align_up((size_t)N * 4, 256);
    int* offs   = (int*)p;   p += align_up((size_t)(N + 1) * 4, 256);
    int* cursor = (int*)p;   p += align_up((size_t)N * 4, 256);
    int* edges4 = (int*)p;   p += align_up(ECAP * 4, 256);
    int2* edges8 = (int2*)p; p += align_up(ECAP * 8, 256);
    float* gate = (float*)p; p += align_up((size_t)D * 4, 256);
    int* bsums  = (int*)p;   p += align_up((size_t)NB * 4, 256);
    short8* Wf_hi = (short8*)p; p += align_up((size_t)3 * 2048 * 16, 256);
    short8* Wf_lo = (short8*)p; p += align_up((size_t)3 * 2048 * 16, 256);
    (void)ws_size; (void)n_in; (void)out_size;

    (void)hipMemsetAsync(counts, 0, (size_t)N * 4, stream);
    (void)hipMemsetAsync(edges4, 0xFF, ECAP * 4, stream);  // pad entries = -1

    int egrid = (E + 255) / 256;
    prep_kernel<<<25 + egrid, 256, 0, stream>>>(
        ei, src32, dst32, counts, E,
        Wl[0], Wl[1], Wl[2], Wf_hi, Wf_lo,
        ts, Wg1, bg1, Wg2, bg2, gate);
    scan_partial_kernel<<<NB, 256, 0, stream>>>(counts, bsums, N);
    scan_bsums_kernel<<<1, 1024, 0, stream>>>(bsums, offs + N, NB);
    scan_final_kernel<<<NB, 256, 0, stream>>>(counts, bsums, offs, cursor, dinv, N);
    bucket_kernel<<<egrid, 256, 0, stream>>>(src32, dst32, cursor, edges4, E);
    int xgrid = (int)((ECAP + 255) / 256);
    expand_kernel<<<xgrid, 256, 0, stream>>>(edges4, dinv, edges8, (int)ECAP);

    int ggrid = (N + GBM - 1) / GBM;
    int agrid = (N + 7) / 8;
    // layer 0: fp32 input, bf16-split path
    gemm_f32_kernel<<<ggrid, 256, 0, stream>>>(x, Wf_hi, Wf_lo, h16, N);
    agg_kernel<<<agrid, 256, 0, stream>>>(h16, edges8, offs, dinv, bl[0], gate,
                                          nullptr, xh, N, 0);
    // layer 1: fp16 single-plane input, fp16 split-W MFMA
    gemm_f16_kernel<<<ggrid, 256, 0, stream>>>(xh, Wf_hi + 2048, Wf_lo + 2048, h16, N);
    agg_kernel<<<agrid, 256, 0, stream>>>(h16, edges8, offs, dinv, bl[1], gate,
                                          nullptr, xh, N, 0);
    // layer 2: fp16 single-plane input, fp32 output
    gemm_f16_kernel<<<ggrid, 256, 0, stream>>>(xh, Wf_hi + 4096, Wf_lo + 4096, h16, N);
    agg_kernel<<<agrid, 256, 0, stream>>>(h16, edges8, offs, dinv, bl[2], gate,
                                          (float*)d_out, nullptr, N, 1);
}

// Round 10
// 237.500 us; speedup vs baseline: 1.0603x; 1.0603x over previous
//
#include <hip/hip_runtime.h>
#include <hip/hip_bf16.h>
#include <hip/hip_fp16.h>
#include <math.h>

// ---------------------------------------------------------------------------
// DynamicGCN: 3x (GCNConv -> ReLU -> *gate)
// R1: multi-block scan, hist fused into convert, dinv folded into scan C.
// R2: split-bf16 MFMA GEMM, W pre-swizzled into B-fragment order.
// R10: agg CSR padded to x4 (tail-free loop); self-edge folded into agg.
// R11: Wf staged per-kc into LDS (double-buffered); X loads global->reg.
// R12: bucket is throughput-bound on scattered partial-line HBM writes;
//     occupancy is NOT the limiter. 8B vs 4B payload dirties SAME lines.
// R13: prep fusion KEPT; heterogeneous block-split fusion REVERTED.
// R17: layers 1/2 fp16 single-plane X + fp16 hi/lo-split W (240.8us).
// R18: cap8 + 8-deep agg REGRESSED (+11us): +29% dummy pad gathers/FMAs,
//     bigger memset/expand, VGPR near the 64 cliff. REVERTED to cap4.
// R19: clean test of the round-latency theory: agg software-pipelined
//     2 rounds deep (meta prefetched 2-ahead, round r+1 gathers ISSUED
//     before round r FMAs) -- 8 gathers in flight, no pad inflation.
//     expand folded into bucket: edges8=(src,dinv[src]) written directly
//     (one L2-hot gather; same dirty lines), expand kernel deleted,
//     memset-0 pads = (0, 0.0f).
// ---------------------------------------------------------------------------

#define D 128   // feature dim (D_IN == HID == 128)

typedef __attribute__((ext_vector_type(8))) short short8;
typedef __attribute__((ext_vector_type(8))) _Float16 half8;
typedef __attribute__((ext_vector_type(4))) float floatx4;

__device__ __forceinline__ unsigned bf16_rne(float x) {
    unsigned u = __float_as_uint(x);
    return (u + 0x7FFFu + ((u >> 16) & 1u)) >> 16;
}

__device__ __forceinline__ void gload_lds16(const void* g, void* l) {
    __builtin_amdgcn_global_load_lds(
        (const __attribute__((address_space(1))) unsigned int*)g,
        (__attribute__((address_space(3))) unsigned int*)l, 16, 0, 0);
}

__device__ __forceinline__ float h2f(unsigned short u) {
    return __half2float(__ushort_as_half(u));
}

// ---- prep: W swizzle (blocks 0..23) + gate MLP (24) + edge convert (25..) -
// Layer 0 fragments: bf16 hi/lo split. Layers 1/2: fp16 hi/lo split.
__global__ __launch_bounds__(256) void prep_kernel(
    const int* __restrict__ w, int* __restrict__ src32,
    int* __restrict__ dst32, int* __restrict__ counts, int E,
    const float* __restrict__ W0, const float* __restrict__ W1,
    const float* __restrict__ W2, short8* __restrict__ Wf_hi,
    short8* __restrict__ Wf_lo,
    const float* __restrict__ t, const float* __restrict__ Wg1,
    const float* __restrict__ bg1, const float* __restrict__ Wg2,
    const float* __restrict__ bg2, float* __restrict__ gate)
{
    int b = blockIdx.x;
    if (b < 24) {
        int f = b * 256 + threadIdx.x;   // 0..6143
        int layer = f >> 11;
        int fi = f & 2047;
        int lane = fi & 63;
        int tt = fi >> 6;                // kc*8 + n
        int kc = tt >> 3, n = tt & 7;
        const float* W = (layer == 0) ? W0 : (layer == 1) ? W1 : W2;
        int krow = kc * 32 + (lane >> 4) * 8;
        int col = n * 16 + (lane & 15);
        short8 hv, lv;
        if (layer == 0) {
            #pragma unroll
            for (int j = 0; j < 8; j++) {
                float x = W[(size_t)(krow + j) * D + col];
                unsigned hb = bf16_rne(x);
                float hf = __uint_as_float(hb << 16);
                unsigned lb = bf16_rne(x - hf);
                hv[j] = (short)hb;
                lv[j] = (short)lb;
            }
        } else {
            #pragma unroll
            for (int j = 0; j < 8; j++) {
                float x = W[(size_t)(krow + j) * D + col];
                __half hh = __float2half(x);
                float hf = __half2float(hh);
                __half ll = __float2half(x - hf);
                hv[j] = (short)__half_as_ushort(hh);
                lv[j] = (short)__half_as_ushort(ll);
            }
        }
        Wf_hi[f] = hv;
        Wf_lo[f] = lv;
        return;
    }
    if (b == 24) {
        __shared__ float u[D];
        int j = threadIdx.x;
        if (j < D) {
            float tv = t[0];
            u[j] = tanhf(tv * Wg1[j] + bg1[j]);
        }
        __syncthreads();
        if (j < D) {
            float s = bg2[j];
            #pragma unroll 8
            for (int k = 0; k < D; k++) s += u[k] * Wg2[k * D + j];
            gate[j] = 1.0f / (1.0f + expf(-s));
        }
        return;
    }
    // ---- edge convert (int64 auto-detect) + fused degree histogram ----
    __shared__ int flag;
    if (threadIdx.x == 0) {
        int z = 0;
        for (int k = 0; k < 64; k++) z |= w[2 * k + 1];
        flag = (z == 0) ? 1 : 0;   // all odd words zero => int64 layout
    }
    __syncthreads();
    int i64 = flag;
    int e = (b - 25) * 256 + threadIdx.x;
    if (e >= E) return;
    int s = i64 ? w[2 * e] : w[e];                       // little-endian low word
    int d = i64 ? w[2 * (E + e)] : w[E + e];
    src32[e] = s;
    dst32[e] = d;
    atomicAdd(&counts[d], 1);
}

// ------------------- multi-block exclusive scan ----------------------------
// Scans CAPACITY = (counts[i]+3)&~3  (external edges padded to x4; self-edge
// is handled inside agg, NOT stored in CSR).
#define SCHUNK 1024
__device__ __forceinline__ int cap4(int c) { return (c + 3) & ~3; }

__global__ __launch_bounds__(256) void scan_partial_kernel(
    const int* __restrict__ counts, int* __restrict__ bsums, int N)
{
    int base = blockIdx.x * SCHUNK + threadIdx.x * 4;
    int s = 0;
    if (base + 3 < N) {
        int4 v = *(const int4*)(counts + base);
        s = cap4(v.x) + cap4(v.y) + cap4(v.z) + cap4(v.w);
    } else {
        for (int k = 0; k < 4; k++) if (base + k < N) s += cap4(counts[base + k]);
    }
    #pragma unroll
    for (int off = 1; off < 64; off <<= 1) s += __shfl_xor(s, off);
    __shared__ int wsum[4];
    int lane = threadIdx.x & 63, wid = threadIdx.x >> 6;
    if (lane == 0) wsum[wid] = s;
    __syncthreads();
    if (threadIdx.x == 0)
        bsums[blockIdx.x] = wsum[0] + wsum[1] + wsum[2] + wsum[3];
}

__global__ __launch_bounds__(1024) void scan_bsums_kernel(
    int* __restrict__ bsums, int* __restrict__ total_out, int B)
{
    int t = threadIdx.x;
    int v = (t < B) ? bsums[t] : 0;
    int lane = t & 63, wid = t >> 6;
    int s = v;
    #pragma unroll
    for (int off = 1; off < 64; off <<= 1) {
        int n = __shfl_up(s, off);
        if (lane >= off) s += n;
    }
    __shared__ int wsum[16], wpre[16];
    if (lane == 63) wsum[wid] = s;
    __syncthreads();
    if (t < 16) {
        int ws = wsum[t];
        #pragma unroll
        for (int off = 1; off < 16; off <<= 1) {
            int n = __shfl_up(ws, off);
            if (t >= off) ws += n;
        }
        wpre[t] = ws;
    }
    __syncthreads();
    int wex = wid ? wpre[wid - 1] : 0;
    if (t < B) bsums[t] = wex + (s - v);      // exclusive
    if (t == 0) *total_out = wpre[15];        // grand total -> offsets[N]
}

__global__ __launch_bounds__(256) void scan_final_kernel(
    const int* __restrict__ counts, const int* __restrict__ bsums,
    int* __restrict__ offsets, int* __restrict__ cursor,
    float* __restrict__ dinv, int N)
{
    int base = blockIdx.x * SCHUNK + threadIdx.x * 4;
    int c[4];
    float dd[4];
    bool full = (base + 3 < N);
    if (full) {
        int4 v = *(const int4*)(counts + base);
        c[0] = cap4(v.x); c[1] = cap4(v.y); c[2] = cap4(v.z); c[3] = cap4(v.w);
        dd[0] = rsqrtf((float)(v.x + 1)); dd[1] = rsqrtf((float)(v.y + 1));
        dd[2] = rsqrtf((float)(v.z + 1)); dd[3] = rsqrtf((float)(v.w + 1));
    } else {
        for (int k = 0; k < 4; k++) {
            int r = (base + k < N) ? counts[base + k] : 0;
            c[k] = (base + k < N) ? cap4(r) : 0;
            dd[k] = rsqrtf((float)(r + 1));
        }
    }
    int sum = c[0] + c[1] + c[2] + c[3];
    int lane = threadIdx.x & 63, wid = threadIdx.x >> 6;
    int s = sum;
    #pragma unroll
    for (int off = 1; off < 64; off <<= 1) {
        int n = __shfl_up(s, off);
        if (lane >= off) s += n;
    }
    __shared__ int wsum[4], wpre[4];
    if (lane == 63) wsum[wid] = s;
    __syncthreads();
    if (threadIdx.x == 0) {
        int a = 0;
        #pragma unroll
        for (int k = 0; k < 4; k++) { wpre[k] = a; a += wsum[k]; }
    }
    __syncthreads();
    int e0 = bsums[blockIdx.x] + wpre[wid] + (s - sum);
    int4 o = make_int4(e0, e0 + c[0], e0 + c[0] + c[1], e0 + c[0] + c[1] + c[2]);
    float4 dv = make_float4(dd[0], dd[1], dd[2], dd[3]);
    if (full) {
        *(int4*)(offsets + base) = o;
        *(int4*)(cursor + base) = o;
        *(float4*)(dinv + base) = dv;
    } else {
        int oo[4] = { o.x, o.y, o.z, o.w };
        for (int k = 0; k < 4; k++)
            if (base + k < N) {
                offsets[base + k] = oo[k];
                cursor[base + k] = oo[k];
                dinv[base + k] = dd[k];
            }
    }
}

// ---------- bucket edges by dst (CSR, (src, dinv[src]) payload) ------------
// One edge per thread: 2 coalesced loads + 1 L2-hot gather -> atomic ->
// 8B scatter (same dirty-line count as 4B, R12/R16 evidence). Pad slots stay
// (0, 0.0f) from the zero-memset -> zero-norm in agg, no masking.
__global__ __launch_bounds__(256) void bucket_kernel(
    const int* __restrict__ src32, const int* __restrict__ dst32,
    const float* __restrict__ dinv, int* __restrict__ cursor,
    int2* __restrict__ edges8, int E)
{
    int e = blockIdx.x * blockDim.x + threadIdx.x;
    if (e >= E) return;
    int s = src32[e];
    int d = dst32[e];
    float f = dinv[s];
    int pos = atomicAdd(&cursor[d], 1);
    edges8[pos] = make_int2(s, __float_as_int(f));
}

// ----- cooperative Wf stage: 16KB (hi 8KB + lo 8KB) per kc into LDS --------
#define WSTAGE(kc_)                                                           \
    {                                                                         \
        short* wb_ = Wfs + (((kc_) & 1) ? 8192 : 0);                          \
        const short8* gh_ = Wf_hi + (size_t)(kc_) * 512;                      \
        const short8* gl_ = Wf_lo + (size_t)(kc_) * 512;                      \
        _Pragma("unroll")                                                     \
        for (int i_ = 0; i_ < 2; i_++) {                                      \
            int c_ = i_ * 256 + w * 64;                                       \
            gload_lds16(gh_ + c_ + lane, wb_ + c_ * 8);                       \
            gload_lds16(gl_ + c_ + lane, wb_ + 4096 + c_ * 8);                \
        }                                                                     \
    }

// ------------- bf16 split MFMA inner block (layer 0) -----------------------
#define MFMA_BLOCK(kc)                                                        \
    {                                                                         \
        const short* wb = Wfs + (((kc) & 1) ? 8192 : 0);                      \
        _Pragma("unroll")                                                     \
        for (int n = 0; n < 8; n++) {                                         \
            short8 bh = *(const short8*)(wb + (n * 64 + lane) * 8);           \
            short8 bl = *(const short8*)(wb + 4096 + (n * 64 + lane) * 8);    \
            acc[0][n] = __builtin_amdgcn_mfma_f32_16x16x32_bf16(ah0, bh, acc[0][n], 0, 0, 0); \
            acc[0][n] = __builtin_amdgcn_mfma_f32_16x16x32_bf16(ah0, bl, acc[0][n], 0, 0, 0); \
            acc[0][n] = __builtin_amdgcn_mfma_f32_16x16x32_bf16(al0, bh, acc[0][n], 0, 0, 0); \
            acc[1][n] = __builtin_amdgcn_mfma_f32_16x16x32_bf16(ah1, bh, acc[1][n], 0, 0, 0); \
            acc[1][n] = __builtin_amdgcn_mfma_f32_16x16x32_bf16(ah1, bl, acc[1][n], 0, 0, 0); \
            acc[1][n] = __builtin_amdgcn_mfma_f32_16x16x32_bf16(al1, bh, acc[1][n], 0, 0, 0); \
        }                                                                     \
    }

// ------------- fp16 split-W MFMA inner block (layers 1/2) ------------------
#define MFMA_BLOCK_F16(kc)                                                    \
    {                                                                         \
        const short* wb = Wfs + (((kc) & 1) ? 8192 : 0);                      \
        _Pragma("unroll")                                                     \
        for (int n = 0; n < 8; n++) {                                         \
            half8 bh = *(const half8*)(wb + (n * 64 + lane) * 8);             \
            half8 bl = *(const half8*)(wb + 4096 + (n * 64 + lane) * 8);      \
            acc[0][n] = __builtin_amdgcn_mfma_f32_16x16x32_f16(ah0, bh, acc[0][n], 0, 0, 0); \
            acc[0][n] = __builtin_amdgcn_mfma_f32_16x16x32_f16(ah0, bl, acc[0][n], 0, 0, 0); \
            acc[1][n] = __builtin_amdgcn_mfma_f32_16x16x32_f16(ah1, bh, acc[1][n], 0, 0, 0); \
            acc[1][n] = __builtin_amdgcn_mfma_f32_16x16x32_f16(ah1, bl, acc[1][n], 0, 0, 0); \
        }                                                                     \
    }

#define EPILOGUE()                                                            \
    _Pragma("unroll")                                                         \
    for (int rt = 0; rt < 2; rt++) {                                          \
        _Pragma("unroll")                                                     \
        for (int reg = 0; reg < 4; reg++) {                                   \
            int row = rowbase + rt * 16 + qd * 4 + reg;                       \
            if (row < M) {                                                    \
                unsigned short* hp = H16 + (size_t)row * D + m16;             \
                _Pragma("unroll")                                             \
                for (int n = 0; n < 8; n++)                                   \
                    hp[n * 16] = __half_as_ushort(__float2half(acc[rt][n][reg])); \
            }                                                                 \
        }                                                                     \
    }

// ------------- GEMM variant A: fp32 X input (layer 0 only) -----------------
#define GBM 128
__device__ __forceinline__ void cvt8(const float* f, short8& hi, short8& lo) {
    #pragma unroll
    for (int j = 0; j < 8; j++) {
        unsigned hb = bf16_rne(f[j]);
        float hf = __uint_as_float(hb << 16);
        unsigned lb = bf16_rne(f[j] - hf);
        hi[j] = (short)hb;
        lo[j] = (short)lb;
    }
}

__global__ __launch_bounds__(256) void gemm_f32_kernel(
    const float* __restrict__ X, const short8* __restrict__ Wf_hi,
    const short8* __restrict__ Wf_lo, unsigned short* __restrict__ H16, int M)
{
    __shared__ short Wfs[16384];   // 32KB: 2 bufs x (hi 8KB + lo 8KB)
    int tid = threadIdx.x;
    int w = tid >> 6, lane = tid & 63;
    int m16 = lane & 15, qd = lane >> 4;
    int rowbase = blockIdx.x * GBM + w * 32;

    int r0 = rowbase + m16;      if (r0 >= M) r0 = M - 1;
    int r1 = rowbase + m16 + 16; if (r1 >= M) r1 = M - 1;
    const float* xp0 = X + (size_t)r0 * D + qd * 8;
    const float* xp1 = X + (size_t)r1 * D + qd * 8;

    floatx4 acc[2][8];
    #pragma unroll
    for (int rt = 0; rt < 2; rt++)
        #pragma unroll
        for (int n = 0; n < 8; n++)
            acc[rt][n] = (floatx4)(0.f);

    #define LOADA(kc_, A0, A1)                                              \
        {                                                                   \
            *(float4*)(A0)     = *(const float4*)(xp0 + (kc_) * 32);        \
            *(float4*)(A0 + 4) = *(const float4*)(xp0 + (kc_) * 32 + 4);    \
            *(float4*)(A1)     = *(const float4*)(xp1 + (kc_) * 32);        \
            *(float4*)(A1 + 4) = *(const float4*)(xp1 + (kc_) * 32 + 4);    \
        }

    float a0c[8], a1c[8], a0n[8], a1n[8];
    WSTAGE(0)
    LOADA(0, a0c, a1c)

    #pragma unroll
    for (int kc = 0; kc < 4; kc++) {
        __syncthreads();     // drains vmcnt: Wf(kc) in LDS, A(kc) in regs
        if (kc < 3) {
            WSTAGE(kc + 1)
            LOADA(kc + 1, a0n, a1n)
        }
        short8 ah0, al0, ah1, al1;
        cvt8(a0c, ah0, al0);
        cvt8(a1c, ah1, al1);
        MFMA_BLOCK(kc)
        if (kc < 3) {
            #pragma unroll
            for (int z = 0; z < 8; z++) { a0c[z] = a0n[z]; a1c[z] = a1n[z]; }
        }
    }
    #undef LOADA
    EPILOGUE()
}

// ------ GEMM variant B: fp16 single-plane X input (layers 1,2) -------------
__global__ __launch_bounds__(256) void gemm_f16_kernel(
    const unsigned short* __restrict__ Xh,
    const short8* __restrict__ Wf_hi, const short8* __restrict__ Wf_lo,
    unsigned short* __restrict__ H16, int M)
{
    __shared__ short Wfs[16384];   // 32KB: 2 bufs x (hi 8KB + lo 8KB)
    int tid = threadIdx.x;
    int w = tid >> 6, lane = tid & 63;
    int m16 = lane & 15, qd = lane >> 4;
    int rowbase = blockIdx.x * GBM + w * 32;

    int r0 = rowbase + m16;      if (r0 >= M) r0 = M - 1;
    int r1 = rowbase + m16 + 16; if (r1 >= M) r1 = M - 1;
    const unsigned short* xh0 = Xh + (size_t)r0 * D + qd * 8;
    const unsigned short* xh1 = Xh + (size_t)r1 * D + qd * 8;

    floatx4 acc[2][8];
    #pragma unroll
    for (int rt = 0; rt < 2; rt++)
        #pragma unroll
        for (int n = 0; n < 8; n++)
            acc[rt][n] = (floatx4)(0.f);

    half8 ah0, ah1, nh0, nh1;
    WSTAGE(0)
    ah0 = *(const half8*)(xh0);
    ah1 = *(const half8*)(xh1);

    #pragma unroll
    for (int kc = 0; kc < 4; kc++) {
        __syncthreads();     // drains vmcnt: Wf(kc) in LDS, A(kc) in regs
        if (kc < 3) {
            WSTAGE(kc + 1)
            nh0 = *(const half8*)(xh0 + (kc + 1) * 32);
            nh1 = *(const half8*)(xh1 + (kc + 1) * 32);
        }
        MFMA_BLOCK_F16(kc)
        if (kc < 3) { ah0 = nh0; ah1 = nh1; }
    }
    EPILOGUE()
}

// ------- per-node aggregation: half-wave/node, 2-round software pipeline ---
// cap4 CSR (pads (0,0.0f) => zero-norm, no masking). Pipeline: meta is
// prefetched TWO rounds ahead and round r+1's 4 gathers ISSUE before round
// r's FMAs consume -- 8 gathers in flight, per-node time ~ 1 gather latency
// instead of rounds x latency. No pad inflation (R18's confound removed).
__global__ __launch_bounds__(256) void agg_kernel(
    const unsigned short* __restrict__ H16, const int2* __restrict__ edges,
    const int* __restrict__ offsets, const float* __restrict__ dinv,
    const float* __restrict__ bias, const float* __restrict__ gate,
    float* __restrict__ outF, unsigned short* __restrict__ outH,
    int M, int writeF32)
{
    int t = threadIdx.x;
    int hw = t >> 5;                  // half-wave 0..7
    int l32 = t & 31;
    int node = blockIdx.x * 8 + hw;
    if (node >= M) return;

    int beg = offsets[node];
    int end = offsets[node + 1];
    float dv = dinv[node];
    const unsigned short* __restrict__ Hc = H16 + l32 * 4;
    // self row: issue load early, consume after the gather loop
    ushort4 us = *(const ushort4*)(Hc + (size_t)node * D);
    float4 acc = make_float4(0.f, 0.f, 0.f, 0.f);

    if (beg < end) {
        // round-0 meta + gathers (in flight)
        int4 p0 = *(const int4*)(edges + beg);       // (s0,f0,s1,f1)
        int4 p1 = *(const int4*)(edges + beg + 2);   // (s2,f2,s3,f3)
        ushort4 u0 = *(const ushort4*)(Hc + (size_t)p0.x * D);
        ushort4 u1 = *(const ushort4*)(Hc + (size_t)p0.z * D);
        ushort4 u2 = *(const ushort4*)(Hc + (size_t)p1.x * D);
        ushort4 u3 = *(const ushort4*)(Hc + (size_t)p1.z * D);
        // round-1 meta
        int j1 = (beg + 4 < end) ? beg + 4 : beg;    // clamped: always valid
        int4 q0 = *(const int4*)(edges + j1);
        int4 q1 = *(const int4*)(edges + j1 + 2);

        for (int j = beg; j < end; j += 4) {
            // meta two rounds ahead (clamped)
            int jn = j + 8;
            int jp = (jn < end) ? jn : beg;
            int4 r0 = *(const int4*)(edges + jp);
            int4 r1 = *(const int4*)(edges + jp + 2);
            // ISSUE next round's gathers before consuming this round
            ushort4 v0 = *(const ushort4*)(Hc + (size_t)q0.x * D);
            ushort4 v1 = *(const ushort4*)(Hc + (size_t)q0.z * D);
            ushort4 v2 = *(const ushort4*)(Hc + (size_t)q1.x * D);
            ushort4 v3 = *(const ushort4*)(Hc + (size_t)q1.z * D);
            // consume round r
            float n0 = __int_as_float(p0.y) * dv, n1 = __int_as_float(p0.w) * dv;
            float n2 = __int_as_float(p1.y) * dv, n3 = __int_as_float(p1.w) * dv;
            acc.x = fmaf(h2f(u3.x), n3, fmaf(h2f(u2.x), n2, fmaf(h2f(u1.x), n1, fmaf(h2f(u0.x), n0, acc.x))));
            acc.y = fmaf(h2f(u3.y), n3, fmaf(h2f(u2.y), n2, fmaf(h2f(u1.y), n1, fmaf(h2f(u0.y), n0, acc.y))));
            acc.z = fmaf(h2f(u3.z), n3, fmaf(h2f(u2.z), n2, fmaf(h2f(u1.z), n1, fmaf(h2f(u0.z), n0, acc.z))));
            acc.w = fmaf(h2f(u3.w), n3, fmaf(h2f(u2.w), n2, fmaf(h2f(u1.w), n1, fmaf(h2f(u0.w), n0, acc.w))));
            // shift pipeline
            p0 = q0; p1 = q1; q0 = r0; q1 = r1;
            u0 = v0; u1 = v1; u2 = v2; u3 = v3;
        }
    }

    // self-loop term: norm = dinv^2 = 1/deg (exact, matches reference)
    float nself = dv * dv;
    acc.x = fmaf(h2f(us.x), nself, acc.x);
    acc.y = fmaf(h2f(us.y), nself, acc.y);
    acc.z = fmaf(h2f(us.z), nself, acc.z);
    acc.w = fmaf(h2f(us.w), nself, acc.w);

    float4 bv = *(const float4*)(bias + l32 * 4);
    float4 gv = *(const float4*)(gate + l32 * 4);
    acc.x = fmaxf(acc.x + bv.x, 0.f) * gv.x;
    acc.y = fmaxf(acc.y + bv.y, 0.f) * gv.y;
    acc.z = fmaxf(acc.z + bv.z, 0.f) * gv.z;
    acc.w = fmaxf(acc.w + bv.w, 0.f) * gv.w;

    if (writeF32) {
        *(float4*)(outF + (size_t)node * D + l32 * 4) = acc;
    } else {
        ushort4 hs = make_ushort4(
            __half_as_ushort(__float2half(acc.x)),
            __half_as_ushort(__float2half(acc.y)),
            __half_as_ushort(__float2half(acc.z)),
            __half_as_ushort(__float2half(acc.w)));
        *(ushort4*)(outH + (size_t)node * D + l32 * 4) = hs;
    }
}

// ---------------------------------------------------------------------------
static inline size_t align_up(size_t v, size_t a) { return (v + a - 1) & ~(a - 1); }

extern "C" void kernel_launch(void* const* d_in, const int* in_sizes, int n_in,
                              void* d_out, int out_size, void* d_ws, size_t ws_size,
                              hipStream_t stream)
{
    const float* x   = (const float*)d_in[0];
    const int*   ei  = (const int*)d_in[1];   // int32 or int64 (auto-detected)
    const float* ts  = (const float*)d_in[2];
    const float* Wl[3] = { (const float*)d_in[3], (const float*)d_in[5], (const float*)d_in[7] };
    const float* bl[3] = { (const float*)d_in[4], (const float*)d_in[6], (const float*)d_in[8] };
    const float* Wg1 = (const float*)d_in[9];
    const float* bg1 = (const float*)d_in[10];
    const float* Wg2 = (const float*)d_in[11];
    const float* bg2 = (const float*)d_in[12];

    const int N = in_sizes[0] / D;      // 100000
    const int E = in_sizes[1] / 2;      // 600000
    const int NB = (N + SCHUNK - 1) / SCHUNK;   // scan blocks
    const size_t ECAP = (size_t)E + 3 * (size_t)N;  // x4-padded CSR worst case

    // workspace carve (all 256B aligned)
    char* p = (char*)d_ws;
    unsigned short* h16 = (unsigned short*)p; p += align_up((size_t)N * D * 2, 256);
    unsigned short* xh  = (unsigned short*)p; p += align_up((size_t)N * D * 2, 256);
    int* src32  = (int*)p;   p += align_up((size_t)E * 4, 256);
    int* dst32  = (int*)p;   p += align_up((size_t)E * 4, 256);
    int* counts = (int*)p;   p += align_up((size_t)N * 4, 256);
    float* dinv = (float*)p; p += align_up((size_t)N * 4, 256);
    int* offs   = (int*)p;   p += align_up((size_t)(N + 1) * 4, 256);
    int* cursor = (int*)p;   p += align_up((size_t)N * 4, 256);
    int2* edges8 = (int2*)p; p += align_up(ECAP * 8, 256);
    float* gate = (float*)p; p += align_up((size_t)D * 4, 256);
    int* bsums  = (int*)p;   p += align_up((size_t)NB * 4, 256);
    short8* Wf_hi = (short8*)p; p += align_up((size_t)3 * 2048 * 16, 256);
    short8* Wf_lo = (short8*)p; p += align_up((size_t)3 * 2048 * 16, 256);
    (void)ws_size; (void)n_in; (void)out_size;

    (void)hipMemsetAsync(counts, 0, (size_t)N * 4, stream);
    (void)hipMemsetAsync(edges8, 0, ECAP * 8, stream);  // pads = (0, 0.0f)

    int egrid = (E + 255) / 256;
    prep_kernel<<<25 + egrid, 256, 0, stream>>>(
        ei, src32, dst32, counts, E,
        Wl[0], Wl[1], Wl[2], Wf_hi, Wf_lo,
        ts, Wg1, bg1, Wg2, bg2, gate);
    scan_partial_kernel<<<NB, 256, 0, stream>>>(counts, bsums, N);
    scan_bsums_kernel<<<1, 1024, 0, stream>>>(bsums, offs + N, NB);
    scan_final_kernel<<<NB, 256, 0, stream>>>(counts, bsums, offs, cursor, dinv, N);
    bucket_kernel<<<egrid, 256, 0, stream>>>(src32, dst32, dinv, cursor, edges8, E);

    int ggrid = (N + GBM - 1) / GBM;
    int agrid = (N + 7) / 8;
    // layer 0: fp32 input, bf16-split path
    gemm_f32_kernel<<<ggrid, 256, 0, stream>>>(x, Wf_hi, Wf_lo, h16, N);
    agg_kernel<<<agrid, 256, 0, stream>>>(h16, edges8, offs, dinv, bl[0], gate,
                                          nullptr, xh, N, 0);
    // layer 1: fp16 single-plane input, fp16 split-W MFMA
    gemm_f16_kernel<<<ggrid, 256, 0, stream>>>(xh, Wf_hi + 2048, Wf_lo + 2048, h16, N);
    agg_kernel<<<agrid, 256, 0, stream>>>(h16, edges8, offs, dinv, bl[1], gate,
                                          nullptr, xh, N, 0);
    // layer 2: fp16 single-plane input, fp32 output
    gemm_f16_kernel<<<ggrid, 256, 0, stream>>>(xh, Wf_hi + 4096, Wf_lo + 4096, h16, N);
    agg_kernel<<<agrid, 256, 0, stream>>>(h16, edges8, offs, dinv, bl[2], gate,
                                          (float*)d_out, nullptr, N, 1);
}

// Round 11
// 226.874 us; speedup vs baseline: 1.1100x; 1.0468x over previous
//
#include <hip/hip_runtime.h>
#include <hip/hip_bf16.h>
#include <hip/hip_fp16.h>
#include <math.h>

// ---------------------------------------------------------------------------
// DynamicGCN: 3x (GCNConv -> ReLU -> *gate)
// R1: multi-block scan, hist fused into convert, dinv folded into scan C.
// R2: split-bf16 MFMA GEMM, W pre-swizzled into B-fragment order.
// R10: agg CSR padded to x4 (tail-free loop); self-edge folded into agg.
// R11: Wf staged per-kc into LDS (double-buffered); X loads global->reg.
// R12: single-pass bucket was throughput-bound on scattered partial-line
//     HBM writes (WRITE == 600k x 64B: same-line stores land on different
//     XCDs' non-coherent L2s at different times -> zero merging).
// R13: prep fusion KEPT; heterogeneous block-split fusion REVERTED.
// R17: layers 1/2 fp16 single-plane X + fp16 hi/lo-split W (240.8us).
// R18: cap8 8-deep agg REGRESSED (pad inflation) -> cap4.
// R19: agg 2-round software pipeline; edges8=(src,dinv[src]) (237.5us).
// R20: CSR build rebuilt as two-pass LDS-binned sort to kill the write
//     wall: binpass (LDS histogram by dst>>8, block-chunk scatter into
//     bucket-contiguous staging: same-block-same-instant writes -> same-XCD
//     L2 merge) + place (one block per bucket: LDS image of padded region,
//     per-dst LDS cursors, fused dinv gather, full-line burst write-out;
//     pads zeroed in LDS -> edges8 memset DELETED). cursor2 init folded
//     into scan_final.
// ---------------------------------------------------------------------------

#define D 128   // feature dim (D_IN == HID == 128)

typedef __attribute__((ext_vector_type(8))) short short8;
typedef __attribute__((ext_vector_type(8))) _Float16 half8;
typedef __attribute__((ext_vector_type(4))) float floatx4;

__device__ __forceinline__ unsigned bf16_rne(float x) {
    unsigned u = __float_as_uint(x);
    return (u + 0x7FFFu + ((u >> 16) & 1u)) >> 16;
}

__device__ __forceinline__ void gload_lds16(const void* g, void* l) {
    __builtin_amdgcn_global_load_lds(
        (const __attribute__((address_space(1))) unsigned int*)g,
        (__attribute__((address_space(3))) unsigned int*)l, 16, 0, 0);
}

__device__ __forceinline__ float h2f(unsigned short u) {
    return __half2float(__ushort_as_half(u));
}

// ---- prep: W swizzle (blocks 0..23) + gate MLP (24) + edge convert (25..) -
// Layer 0 fragments: bf16 hi/lo split. Layers 1/2: fp16 hi/lo split.
__global__ __launch_bounds__(256) void prep_kernel(
    const int* __restrict__ w, int* __restrict__ src32,
    int* __restrict__ dst32, int* __restrict__ counts, int E,
    const float* __restrict__ W0, const float* __restrict__ W1,
    const float* __restrict__ W2, short8* __restrict__ Wf_hi,
    short8* __restrict__ Wf_lo,
    const float* __restrict__ t, const float* __restrict__ Wg1,
    const float* __restrict__ bg1, const float* __restrict__ Wg2,
    const float* __restrict__ bg2, float* __restrict__ gate)
{
    int b = blockIdx.x;
    if (b < 24) {
        int f = b * 256 + threadIdx.x;   // 0..6143
        int layer = f >> 11;
        int fi = f & 2047;
        int lane = fi & 63;
        int tt = fi >> 6;                // kc*8 + n
        int kc = tt >> 3, n = tt & 7;
        const float* W = (layer == 0) ? W0 : (layer == 1) ? W1 : W2;
        int krow = kc * 32 + (lane >> 4) * 8;
        int col = n * 16 + (lane & 15);
        short8 hv, lv;
        if (layer == 0) {
            #pragma unroll
            for (int j = 0; j < 8; j++) {
                float x = W[(size_t)(krow + j) * D + col];
                unsigned hb = bf16_rne(x);
                float hf = __uint_as_float(hb << 16);
                unsigned lb = bf16_rne(x - hf);
                hv[j] = (short)hb;
                lv[j] = (short)lb;
            }
        } else {
            #pragma unroll
            for (int j = 0; j < 8; j++) {
                float x = W[(size_t)(krow + j) * D + col];
                __half hh = __float2half(x);
                float hf = __half2float(hh);
                __half ll = __float2half(x - hf);
                hv[j] = (short)__half_as_ushort(hh);
                lv[j] = (short)__half_as_ushort(ll);
            }
        }
        Wf_hi[f] = hv;
        Wf_lo[f] = lv;
        return;
    }
    if (b == 24) {
        __shared__ float u[D];
        int j = threadIdx.x;
        if (j < D) {
            float tv = t[0];
            u[j] = tanhf(tv * Wg1[j] + bg1[j]);
        }
        __syncthreads();
        if (j < D) {
            float s = bg2[j];
            #pragma unroll 8
            for (int k = 0; k < D; k++) s += u[k] * Wg2[k * D + j];
            gate[j] = 1.0f / (1.0f + expf(-s));
        }
        return;
    }
    // ---- edge convert (int64 auto-detect) + fused degree histogram ----
    __shared__ int flag;
    if (threadIdx.x == 0) {
        int z = 0;
        for (int k = 0; k < 64; k++) z |= w[2 * k + 1];
        flag = (z == 0) ? 1 : 0;   // all odd words zero => int64 layout
    }
    __syncthreads();
    int i64 = flag;
    int e = (b - 25) * 256 + threadIdx.x;
    if (e >= E) return;
    int s = i64 ? w[2 * e] : w[e];                       // little-endian low word
    int d = i64 ? w[2 * (E + e)] : w[E + e];
    src32[e] = s;
    dst32[e] = d;
    atomicAdd(&counts[d], 1);
}

// ------------------- multi-block exclusive scan ----------------------------
// Scans CAPACITY = (counts[i]+3)&~3  (external edges padded to x4; self-edge
// is handled inside agg, NOT stored in CSR).
#define SCHUNK 1024
#define RBITS 8
#define RSZ 256            // dsts per coarse bucket (place region)
__device__ __forceinline__ int cap4(int c) { return (c + 3) & ~3; }

__global__ __launch_bounds__(256) void scan_partial_kernel(
    const int* __restrict__ counts, int* __restrict__ bsums, int N)
{
    int base = blockIdx.x * SCHUNK + threadIdx.x * 4;
    int s = 0;
    if (base + 3 < N) {
        int4 v = *(const int4*)(counts + base);
        s = cap4(v.x) + cap4(v.y) + cap4(v.z) + cap4(v.w);
    } else {
        for (int k = 0; k < 4; k++) if (base + k < N) s += cap4(counts[base + k]);
    }
    #pragma unroll
    for (int off = 1; off < 64; off <<= 1) s += __shfl_xor(s, off);
    __shared__ int wsum[4];
    int lane = threadIdx.x & 63, wid = threadIdx.x >> 6;
    if (lane == 0) wsum[wid] = s;
    __syncthreads();
    if (threadIdx.x == 0)
        bsums[blockIdx.x] = wsum[0] + wsum[1] + wsum[2] + wsum[3];
}

__global__ __launch_bounds__(1024) void scan_bsums_kernel(
    int* __restrict__ bsums, int* __restrict__ total_out, int B)
{
    int t = threadIdx.x;
    int v = (t < B) ? bsums[t] : 0;
    int lane = t & 63, wid = t >> 6;
    int s = v;
    #pragma unroll
    for (int off = 1; off < 64; off <<= 1) {
        int n = __shfl_up(s, off);
        if (lane >= off) s += n;
    }
    __shared__ int wsum[16], wpre[16];
    if (lane == 63) wsum[wid] = s;
    __syncthreads();
    if (t < 16) {
        int ws = wsum[t];
        #pragma unroll
        for (int off = 1; off < 16; off <<= 1) {
            int n = __shfl_up(ws, off);
            if (t >= off) ws += n;
        }
        wpre[t] = ws;
    }
    __syncthreads();
    int wex = wid ? wpre[wid - 1] : 0;
    if (t < B) bsums[t] = wex + (s - v);      // exclusive
    if (t == 0) *total_out = wpre[15];        // grand total -> offsets[N]
}

__global__ __launch_bounds__(256) void scan_final_kernel(
    const int* __restrict__ counts, const int* __restrict__ bsums,
    int* __restrict__ offsets, int* __restrict__ cursor2,
    float* __restrict__ dinv, int N)
{
    int base = blockIdx.x * SCHUNK + threadIdx.x * 4;
    int c[4];
    float dd[4];
    bool full = (base + 3 < N);
    if (full) {
        int4 v = *(const int4*)(counts + base);
        c[0] = cap4(v.x); c[1] = cap4(v.y); c[2] = cap4(v.z); c[3] = cap4(v.w);
        dd[0] = rsqrtf((float)(v.x + 1)); dd[1] = rsqrtf((float)(v.y + 1));
        dd[2] = rsqrtf((float)(v.z + 1)); dd[3] = rsqrtf((float)(v.w + 1));
    } else {
        for (int k = 0; k < 4; k++) {
            int r = (base + k < N) ? counts[base + k] : 0;
            c[k] = (base + k < N) ? cap4(r) : 0;
            dd[k] = rsqrtf((float)(r + 1));
        }
    }
    int sum = c[0] + c[1] + c[2] + c[3];
    int lane = threadIdx.x & 63, wid = threadIdx.x >> 6;
    int s = sum;
    #pragma unroll
    for (int off = 1; off < 64; off <<= 1) {
        int n = __shfl_up(s, off);
        if (lane >= off) s += n;
    }
    __shared__ int wsum[4], wpre[4];
    if (lane == 63) wsum[wid] = s;
    __syncthreads();
    if (threadIdx.x == 0) {
        int a = 0;
        #pragma unroll
        for (int k = 0; k < 4; k++) { wpre[k] = a; a += wsum[k]; }
    }
    __syncthreads();
    int e0 = bsums[blockIdx.x] + wpre[wid] + (s - sum);
    int4 o = make_int4(e0, e0 + c[0], e0 + c[0] + c[1], e0 + c[0] + c[1] + c[2]);
    float4 dv = make_float4(dd[0], dd[1], dd[2], dd[3]);
    if (full) {
        *(int4*)(offsets + base) = o;
        *(float4*)(dinv + base) = dv;
    } else {
        int oo[4] = { o.x, o.y, o.z, o.w };
        for (int k = 0; k < 4; k++)
            if (base + k < N) {
                offsets[base + k] = oo[k];
                dinv[base + k] = dd[k];
            }
    }
    // staging cursor for coarse bucket starting at this node (RSZ | base ok:
    // RSZ=256 is a multiple of the 4-node quad, so bucket starts align).
    if ((base & (RSZ - 1)) == 0 && base < N) cursor2[base >> RBITS] = e0;
}

// ----- pass 1: LDS-binned scatter into bucket-contiguous staging -----------
// Each block: 4096 edges -> LDS histogram over dst>>8 buckets -> one global
// atomicAdd per (block,bin) -> scatter (src,dst) into the bucket's staging
// chunk. A block's per-bin chunk is written at one instant from one block
// (= one XCD) -> lines merge in that XCD's L2.
#define P1E 16
__global__ __launch_bounds__(256) void binpass_kernel(
    const int* __restrict__ src32, const int* __restrict__ dst32,
    int* __restrict__ cursor2, int2* __restrict__ stag, int E, int B)
{
    __shared__ int cnt[512];
    __shared__ int base[512];
    int tid = threadIdx.x;
    for (int i = tid; i < B; i += 256) cnt[i] = 0;
    __syncthreads();
    int e0 = blockIdx.x * (P1E * 256) + tid;
    int s[P1E], d[P1E], lp[P1E];
    #pragma unroll
    for (int k = 0; k < P1E; k++) {
        int e = e0 + k * 256;
        if (e < E) {
            s[k] = src32[e];
            d[k] = dst32[e];
            lp[k] = atomicAdd(&cnt[d[k] >> RBITS], 1);
        }
    }
    __syncthreads();
    for (int i = tid; i < B; i += 256)
        base[i] = cnt[i] ? atomicAdd(&cursor2[i], cnt[i]) : 0;
    __syncthreads();
    #pragma unroll
    for (int k = 0; k < P1E; k++) {
        int e = e0 + k * 256;
        if (e < E)
            stag[base[d[k] >> RBITS] + lp[k]] = make_int2(s[k], d[k]);
    }
}

// ----- pass 2: one block per bucket: order region in LDS, burst write ------
// LDS image of the padded CSR region (zero-init -> pads come out (0,0.0f)),
// per-dst LDS cursors place edges at offs[d]+k, dinv gather fused, then the
// whole region is written out fully coalesced (full-line bursts).
// edges8 memset is no longer needed.
#define P2CAP 4096   // 32KB LDS image
__global__ __launch_bounds__(256) void place_kernel(
    const int2* __restrict__ stag, const int* __restrict__ cursor2,
    const int* __restrict__ offsets, const float* __restrict__ dinv,
    int2* __restrict__ edges8, int N)
{
    __shared__ int2 buf[P2CAP];
    __shared__ int loff[RSZ + 1];
    __shared__ int lcnt[RSZ];
    int b = blockIdx.x;
    int tid = threadIdx.x;
    int d0 = b * RSZ;
    int d1 = (d0 + RSZ < N) ? d0 + RSZ : N;
    int nd = d1 - d0;
    for (int i = tid; i <= nd; i += 256) loff[i] = offsets[d0 + i];
    for (int i = tid; i < nd; i += 256) lcnt[i] = 0;
    __syncthreads();
    int regionStart = loff[0];
    int regionSize = loff[nd] - regionStart;
    int ecount = cursor2[b] - regionStart;
    if (regionSize <= P2CAP) {
        for (int i = tid; i < regionSize; i += 256) buf[i] = make_int2(0, 0);
        __syncthreads();
        for (int i = tid; i < ecount; i += 256) {
            int2 sd = stag[regionStart + i];
            int ld = sd.y - d0;
            int pos = loff[ld] - regionStart + atomicAdd(&lcnt[ld], 1);
            buf[pos] = make_int2(sd.x, __float_as_int(dinv[sd.x]));
        }
        __syncthreads();
        for (int i = tid; i < regionSize; i += 256)
            edges8[regionStart + i] = buf[i];
    } else {
        // fallback (degenerate degree distribution): zero region, scatter
        for (int i = tid; i < regionSize; i += 256)
            edges8[regionStart + i] = make_int2(0, 0);
        __syncthreads();
        for (int i = tid; i < ecount; i += 256) {
            int2 sd = stag[regionStart + i];
            int ld = sd.y - d0;
            int pos = loff[ld] + atomicAdd(&lcnt[ld], 1);
            edges8[pos] = make_int2(sd.x, __float_as_int(dinv[sd.x]));
        }
    }
}

// ----- cooperative Wf stage: 16KB (hi 8KB + lo 8KB) per kc into LDS --------
#define WSTAGE(kc_)                                                           \
    {                                                                         \
        short* wb_ = Wfs + (((kc_) & 1) ? 8192 : 0);                          \
        const short8* gh_ = Wf_hi + (size_t)(kc_) * 512;                      \
        const short8* gl_ = Wf_lo + (size_t)(kc_) * 512;                      \
        _Pragma("unroll")                                                     \
        for (int i_ = 0; i_ < 2; i_++) {                                      \
            int c_ = i_ * 256 + w * 64;                                       \
            gload_lds16(gh_ + c_ + lane, wb_ + c_ * 8);                       \
            gload_lds16(gl_ + c_ + lane, wb_ + 4096 + c_ * 8);                \
        }                                                                     \
    }

// ------------- bf16 split MFMA inner block (layer 0) -----------------------
#define MFMA_BLOCK(kc)                                                        \
    {                                                                         \
        const short* wb = Wfs + (((kc) & 1) ? 8192 : 0);                      \
        _Pragma("unroll")                                                     \
        for (int n = 0; n < 8; n++) {                                         \
            short8 bh = *(const short8*)(wb + (n * 64 + lane) * 8);           \
            short8 bl = *(const short8*)(wb + 4096 + (n * 64 + lane) * 8);    \
            acc[0][n] = __builtin_amdgcn_mfma_f32_16x16x32_bf16(ah0, bh, acc[0][n], 0, 0, 0); \
            acc[0][n] = __builtin_amdgcn_mfma_f32_16x16x32_bf16(ah0, bl, acc[0][n], 0, 0, 0); \
            acc[0][n] = __builtin_amdgcn_mfma_f32_16x16x32_bf16(al0, bh, acc[0][n], 0, 0, 0); \
            acc[1][n] = __builtin_amdgcn_mfma_f32_16x16x32_bf16(ah1, bh, acc[1][n], 0, 0, 0); \
            acc[1][n] = __builtin_amdgcn_mfma_f32_16x16x32_bf16(ah1, bl, acc[1][n], 0, 0, 0); \
            acc[1][n] = __builtin_amdgcn_mfma_f32_16x16x32_bf16(al1, bh, acc[1][n], 0, 0, 0); \
        }                                                                     \
    }

// ------------- fp16 split-W MFMA inner block (layers 1/2) ------------------
#define MFMA_BLOCK_F16(kc)                                                    \
    {                                                                         \
        const short* wb = Wfs + (((kc) & 1) ? 8192 : 0);                      \
        _Pragma("unroll")                                                     \
        for (int n = 0; n < 8; n++) {                                         \
            half8 bh = *(const half8*)(wb + (n * 64 + lane) * 8);             \
            half8 bl = *(const half8*)(wb + 4096 + (n * 64 + lane) * 8);      \
            acc[0][n] = __builtin_amdgcn_mfma_f32_16x16x32_f16(ah0, bh, acc[0][n], 0, 0, 0); \
            acc[0][n] = __builtin_amdgcn_mfma_f32_16x16x32_f16(ah0, bl, acc[0][n], 0, 0, 0); \
            acc[1][n] = __builtin_amdgcn_mfma_f32_16x16x32_f16(ah1, bh, acc[1][n], 0, 0, 0); \
            acc[1][n] = __builtin_amdgcn_mfma_f32_16x16x32_f16(ah1, bl, acc[1][n], 0, 0, 0); \
        }                                                                     \
    }

#define EPILOGUE()                                                            \
    _Pragma("unroll")                                                         \
    for (int rt = 0; rt < 2; rt++) {                                          \
        _Pragma("unroll")                                                     \
        for (int reg = 0; reg < 4; reg++) {                                   \
            int row = rowbase + rt * 16 + qd * 4 + reg;                       \
            if (row < M) {                                                    \
                unsigned short* hp = H16 + (size_t)row * D + m16;             \
                _Pragma("unroll")                                             \
                for (int n = 0; n < 8; n++)                                   \
                    hp[n * 16] = __half_as_ushort(__float2half(acc[rt][n][reg])); \
            }                                                                 \
        }                                                                     \
    }

// ------------- GEMM variant A: fp32 X input (layer 0 only) -----------------
#define GBM 128
__device__ __forceinline__ void cvt8(const float* f, short8& hi, short8& lo) {
    #pragma unroll
    for (int j = 0; j < 8; j++) {
        unsigned hb = bf16_rne(f[j]);
        float hf = __uint_as_float(hb << 16);
        unsigned lb = bf16_rne(f[j] - hf);
        hi[j] = (short)hb;
        lo[j] = (short)lb;
    }
}

__global__ __launch_bounds__(256) void gemm_f32_kernel(
    const float* __restrict__ X, const short8* __restrict__ Wf_hi,
    const short8* __restrict__ Wf_lo, unsigned short* __restrict__ H16, int M)
{
    __shared__ short Wfs[16384];   // 32KB: 2 bufs x (hi 8KB + lo 8KB)
    int tid = threadIdx.x;
    int w = tid >> 6, lane = tid & 63;
    int m16 = lane & 15, qd = lane >> 4;
    int rowbase = blockIdx.x * GBM + w * 32;

    int r0 = rowbase + m16;      if (r0 >= M) r0 = M - 1;
    int r1 = rowbase + m16 + 16; if (r1 >= M) r1 = M - 1;
    const float* xp0 = X + (size_t)r0 * D + qd * 8;
    const float* xp1 = X + (size_t)r1 * D + qd * 8;

    floatx4 acc[2][8];
    #pragma unroll
    for (int rt = 0; rt < 2; rt++)
        #pragma unroll
        for (int n = 0; n < 8; n++)
            acc[rt][n] = (floatx4)(0.f);

    #define LOADA(kc_, A0, A1)                                              \
        {                                                                   \
            *(float4*)(A0)     = *(const float4*)(xp0 + (kc_) * 32);        \
            *(float4*)(A0 + 4) = *(const float4*)(xp0 + (kc_) * 32 + 4);    \
            *(float4*)(A1)     = *(const float4*)(xp1 + (kc_) * 32);        \
            *(float4*)(A1 + 4) = *(const float4*)(xp1 + (kc_) * 32 + 4);    \
        }

    float a0c[8], a1c[8], a0n[8], a1n[8];
    WSTAGE(0)
    LOADA(0, a0c, a1c)

    #pragma unroll
    for (int kc = 0; kc < 4; kc++) {
        __syncthreads();     // drains vmcnt: Wf(kc) in LDS, A(kc) in regs
        if (kc < 3) {
            WSTAGE(kc + 1)
            LOADA(kc + 1, a0n, a1n)
        }
        short8 ah0, al0, ah1, al1;
        cvt8(a0c, ah0, al0);
        cvt8(a1c, ah1, al1);
        MFMA_BLOCK(kc)
        if (kc < 3) {
            #pragma unroll
            for (int z = 0; z < 8; z++) { a0c[z] = a0n[z]; a1c[z] = a1n[z]; }
        }
    }
    #undef LOADA
    EPILOGUE()
}

// ------ GEMM variant B: fp16 single-plane X input (layers 1,2) -------------
__global__ __launch_bounds__(256) void gemm_f16_kernel(
    const unsigned short* __restrict__ Xh,
    const short8* __restrict__ Wf_hi, const short8* __restrict__ Wf_lo,
    unsigned short* __restrict__ H16, int M)
{
    __shared__ short Wfs[16384];   // 32KB: 2 bufs x (hi 8KB + lo 8KB)
    int tid = threadIdx.x;
    int w = tid >> 6, lane = tid & 63;
    int m16 = lane & 15, qd = lane >> 4;
    int rowbase = blockIdx.x * GBM + w * 32;

    int r0 = rowbase + m16;      if (r0 >= M) r0 = M - 1;
    int r1 = rowbase + m16 + 16; if (r1 >= M) r1 = M - 1;
    const unsigned short* xh0 = Xh + (size_t)r0 * D + qd * 8;
    const unsigned short* xh1 = Xh + (size_t)r1 * D + qd * 8;

    floatx4 acc[2][8];
    #pragma unroll
    for (int rt = 0; rt < 2; rt++)
        #pragma unroll
        for (int n = 0; n < 8; n++)
            acc[rt][n] = (floatx4)(0.f);

    half8 ah0, ah1, nh0, nh1;
    WSTAGE(0)
    ah0 = *(const half8*)(xh0);
    ah1 = *(const half8*)(xh1);

    #pragma unroll
    for (int kc = 0; kc < 4; kc++) {
        __syncthreads();     // drains vmcnt: Wf(kc) in LDS, A(kc) in regs
        if (kc < 3) {
            WSTAGE(kc + 1)
            nh0 = *(const half8*)(xh0 + (kc + 1) * 32);
            nh1 = *(const half8*)(xh1 + (kc + 1) * 32);
        }
        MFMA_BLOCK_F16(kc)
        if (kc < 3) { ah0 = nh0; ah1 = nh1; }
    }
    EPILOGUE()
}

// ------- per-node aggregation: half-wave/node, 2-round software pipeline ---
// cap4 CSR (pads (0,0.0f) => zero-norm, no masking). Meta prefetched two
// rounds ahead; round r+1's gathers issue before round r's FMAs consume.
__global__ __launch_bounds__(256) void agg_kernel(
    const unsigned short* __restrict__ H16, const int2* __restrict__ edges,
    const int* __restrict__ offsets, const float* __restrict__ dinv,
    const float* __restrict__ bias, const float* __restrict__ gate,
    float* __restrict__ outF, unsigned short* __restrict__ outH,
    int M, int writeF32)
{
    int t = threadIdx.x;
    int hw = t >> 5;                  // half-wave 0..7
    int l32 = t & 31;
    int node = blockIdx.x * 8 + hw;
    if (node >= M) return;

    int beg = offsets[node];
    int end = offsets[node + 1];
    float dv = dinv[node];
    const unsigned short* __restrict__ Hc = H16 + l32 * 4;
    // self row: issue load early, consume after the gather loop
    ushort4 us = *(const ushort4*)(Hc + (size_t)node * D);
    float4 acc = make_float4(0.f, 0.f, 0.f, 0.f);

    if (beg < end) {
        // round-0 meta + gathers (in flight)
        int4 p0 = *(const int4*)(edges + beg);       // (s0,f0,s1,f1)
        int4 p1 = *(const int4*)(edges + beg + 2);   // (s2,f2,s3,f3)
        ushort4 u0 = *(const ushort4*)(Hc + (size_t)p0.x * D);
        ushort4 u1 = *(const ushort4*)(Hc + (size_t)p0.z * D);
        ushort4 u2 = *(const ushort4*)(Hc + (size_t)p1.x * D);
        ushort4 u3 = *(const ushort4*)(Hc + (size_t)p1.z * D);
        // round-1 meta
        int j1 = (beg + 4 < end) ? beg + 4 : beg;    // clamped: always valid
        int4 q0 = *(const int4*)(edges + j1);
        int4 q1 = *(const int4*)(edges + j1 + 2);

        for (int j = beg; j < end; j += 4) {
            // meta two rounds ahead (clamped)
            int jn = j + 8;
            int jp = (jn < end) ? jn : beg;
            int4 r0 = *(const int4*)(edges + jp);
            int4 r1 = *(const int4*)(edges + jp + 2);
            // ISSUE next round's gathers before consuming this round
            ushort4 v0 = *(const ushort4*)(Hc + (size_t)q0.x * D);
            ushort4 v1 = *(const ushort4*)(Hc + (size_t)q0.z * D);
            ushort4 v2 = *(const ushort4*)(Hc + (size_t)q1.x * D);
            ushort4 v3 = *(const ushort4*)(Hc + (size_t)q1.z * D);
            // consume round r
            float n0 = __int_as_float(p0.y) * dv, n1 = __int_as_float(p0.w) * dv;
            float n2 = __int_as_float(p1.y) * dv, n3 = __int_as_float(p1.w) * dv;
            acc.x = fmaf(h2f(u3.x), n3, fmaf(h2f(u2.x), n2, fmaf(h2f(u1.x), n1, fmaf(h2f(u0.x), n0, acc.x))));
            acc.y = fmaf(h2f(u3.y), n3, fmaf(h2f(u2.y), n2, fmaf(h2f(u1.y), n1, fmaf(h2f(u0.y), n0, acc.y))));
            acc.z = fmaf(h2f(u3.z), n3, fmaf(h2f(u2.z), n2, fmaf(h2f(u1.z), n1, fmaf(h2f(u0.z), n0, acc.z))));
            acc.w = fmaf(h2f(u3.w), n3, fmaf(h2f(u2.w), n2, fmaf(h2f(u1.w), n1, fmaf(h2f(u0.w), n0, acc.w))));
            // shift pipeline
            p0 = q0; p1 = q1; q0 = r0; q1 = r1;
            u0 = v0; u1 = v1; u2 = v2; u3 = v3;
        }
    }

    // self-loop term: norm = dinv^2 = 1/deg (exact, matches reference)
    float nself = dv * dv;
    acc.x = fmaf(h2f(us.x), nself, acc.x);
    acc.y = fmaf(h2f(us.y), nself, acc.y);
    acc.z = fmaf(h2f(us.z), nself, acc.z);
    acc.w = fmaf(h2f(us.w), nself, acc.w);

    float4 bv = *(const float4*)(bias + l32 * 4);
    float4 gv = *(const float4*)(gate + l32 * 4);
    acc.x = fmaxf(acc.x + bv.x, 0.f) * gv.x;
    acc.y = fmaxf(acc.y + bv.y, 0.f) * gv.y;
    acc.z = fmaxf(acc.z + bv.z, 0.f) * gv.z;
    acc.w = fmaxf(acc.w + bv.w, 0.f) * gv.w;

    if (writeF32) {
        *(float4*)(outF + (size_t)node * D + l32 * 4) = acc;
    } else {
        ushort4 hs = make_ushort4(
            __half_as_ushort(__float2half(acc.x)),
            __half_as_ushort(__float2half(acc.y)),
            __half_as_ushort(__float2half(acc.z)),
            __half_as_ushort(__float2half(acc.w)));
        *(ushort4*)(outH + (size_t)node * D + l32 * 4) = hs;
    }
}

// ---------------------------------------------------------------------------
static inline size_t align_up(size_t v, size_t a) { return (v + a - 1) & ~(a - 1); }

extern "C" void kernel_launch(void* const* d_in, const int* in_sizes, int n_in,
                              void* d_out, int out_size, void* d_ws, size_t ws_size,
                              hipStream_t stream)
{
    const float* x   = (const float*)d_in[0];
    const int*   ei  = (const int*)d_in[1];   // int32 or int64 (auto-detected)
    const float* ts  = (const float*)d_in[2];
    const float* Wl[3] = { (const float*)d_in[3], (const float*)d_in[5], (const float*)d_in[7] };
    const float* bl[3] = { (const float*)d_in[4], (const float*)d_in[6], (const float*)d_in[8] };
    const float* Wg1 = (const float*)d_in[9];
    const float* bg1 = (const float*)d_in[10];
    const float* Wg2 = (const float*)d_in[11];
    const float* bg2 = (const float*)d_in[12];

    const int N = in_sizes[0] / D;      // 100000
    const int E = in_sizes[1] / 2;      // 600000
    const int NB = (N + SCHUNK - 1) / SCHUNK;   // scan blocks
    const int B  = (N + RSZ - 1) / RSZ;         // coarse buckets (391)
    const size_t ECAP = (size_t)E + 3 * (size_t)N;  // x4-padded CSR worst case

    // workspace carve (all 256B aligned)
    char* p = (char*)d_ws;
    unsigned short* h16 = (unsigned short*)p; p += align_up((size_t)N * D * 2, 256);
    unsigned short* xh  = (unsigned short*)p; p += align_up((size_t)N * D * 2, 256);
    int* src32  = (int*)p;   p += align_up((size_t)E * 4, 256);
    int* dst32  = (int*)p;   p += align_up((size_t)E * 4, 256);
    int* counts = (int*)p;   p += align_up((size_t)N * 4, 256);
    float* dinv = (float*)p; p += align_up((size_t)N * 4, 256);
    int* offs   = (int*)p;   p += align_up((size_t)(N + 1) * 4, 256);
    int* cursor2 = (int*)p;  p += align_up((size_t)B * 4, 256);
    int2* stag  = (int2*)p;  p += align_up(ECAP * 8, 256);
    int2* edges8 = (int2*)p; p += align_up(ECAP * 8, 256);
    float* gate = (float*)p; p += align_up((size_t)D * 4, 256);
    int* bsums  = (int*)p;   p += align_up((size_t)NB * 4, 256);
    short8* Wf_hi = (short8*)p; p += align_up((size_t)3 * 2048 * 16, 256);
    short8* Wf_lo = (short8*)p; p += align_up((size_t)3 * 2048 * 16, 256);
    (void)ws_size; (void)n_in; (void)out_size;

    (void)hipMemsetAsync(counts, 0, (size_t)N * 4, stream);

    int egrid = (E + 255) / 256;
    prep_kernel<<<25 + egrid, 256, 0, stream>>>(
        ei, src32, dst32, counts, E,
        Wl[0], Wl[1], Wl[2], Wf_hi, Wf_lo,
        ts, Wg1, bg1, Wg2, bg2, gate);
    scan_partial_kernel<<<NB, 256, 0, stream>>>(counts, bsums, N);
    scan_bsums_kernel<<<1, 1024, 0, stream>>>(bsums, offs + N, NB);
    scan_final_kernel<<<NB, 256, 0, stream>>>(counts, bsums, offs, cursor2, dinv, N);
    int g1 = (E + P1E * 256 - 1) / (P1E * 256);
    binpass_kernel<<<g1, 256, 0, stream>>>(src32, dst32, cursor2, stag, E, B);
    place_kernel<<<B, 256, 0, stream>>>(stag, cursor2, offs, dinv, edges8, N);

    int ggrid = (N + GBM - 1) / GBM;
    int agrid = (N + 7) / 8;
    // layer 0: fp32 input, bf16-split path
    gemm_f32_kernel<<<ggrid, 256, 0, stream>>>(x, Wf_hi, Wf_lo, h16, N);
    agg_kernel<<<agrid, 256, 0, stream>>>(h16, edges8, offs, dinv, bl[0], gate,
                                          nullptr, xh, N, 0);
    // layer 1: fp16 single-plane input, fp16 split-W MFMA
    gemm_f16_kernel<<<ggrid, 256, 0, stream>>>(xh, Wf_hi + 2048, Wf_lo + 2048, h16, N);
    agg_kernel<<<agrid, 256, 0, stream>>>(h16, edges8, offs, dinv, bl[1], gate,
                                          nullptr, xh, N, 0);
    // layer 2: fp16 single-plane input, fp32 output
    gemm_f16_kernel<<<ggrid, 256, 0, stream>>>(xh, Wf_hi + 4096, Wf_lo + 4096, h16, N);
    agg_kernel<<<agrid, 256, 0, stream>>>(h16, edges8, offs, dinv, bl[2], gate,
                                          (float*)d_out, nullptr, N, 1);
}

// Round 12
// 195.314 us; speedup vs baseline: 1.2893x; 1.1616x over previous
//
#include <hip/hip_runtime.h>
#include <hip/hip_bf16.h>
#include <hip/hip_fp16.h>
#include <math.h>

// ---------------------------------------------------------------------------
// DynamicGCN: 3x (GCNConv -> ReLU -> *gate)
// R2: split-bf16 MFMA GEMM, W pre-swizzled into B-fragment order.
// R10: agg CSR padded to x4 (tail-free loop); self-edge folded into agg.
// R11: Wf staged per-kc into LDS (double-buffered); X loads global->reg.
// R12: scattered partial-line HBM writes don't merge across XCDs.
// R13: prep fusion KEPT; heterogeneous block-split fusion REVERTED.
// R17: layers 1/2 fp16 single-plane X + fp16 hi/lo-split W (240.8us).
// R19: agg 2-round software pipeline (237.5us).
// R20: two-pass LDS-binned CSR build (binpass+place), killing the write
//     wall (226.9us).
// R21: fixed-slot staging (SCAP=RCAP=4096/bucket) deletes ALL global scans
//     + prep's 600k scattered hist atomics + counts memset: binpass needs
//     only cursor2[b]=b*SCAP (init in prep); new place1 recomputes per-dst
//     degrees from staged edges in LDS (prefix -> obeg/oend/dinv coalesced);
//     place2 builds edges8; agg reads obeg/oend. Overflow guards (never hit
//     for uniform input, margin >2x) prevent corruption on degenerate input.
// ---------------------------------------------------------------------------

#define D 128   // feature dim (D_IN == HID == 128)

typedef __attribute__((ext_vector_type(8))) short short8;
typedef __attribute__((ext_vector_type(8))) _Float16 half8;
typedef __attribute__((ext_vector_type(4))) float floatx4;

#define RBITS 8
#define RSZ 256            // dsts per coarse bucket
#define SCAP 4096          // staging slot entries per bucket (max ~1730)
#define RCAP 4096          // edges8 slot entries per bucket (max cap ~2500)

__device__ __forceinline__ unsigned bf16_rne(float x) {
    unsigned u = __float_as_uint(x);
    return (u + 0x7FFFu + ((u >> 16) & 1u)) >> 16;
}

__device__ __forceinline__ void gload_lds16(const void* g, void* l) {
    __builtin_amdgcn_global_load_lds(
        (const __attribute__((address_space(1))) unsigned int*)g,
        (__attribute__((address_space(3))) unsigned int*)l, 16, 0, 0);
}

__device__ __forceinline__ float h2f(unsigned short u) {
    return __half2float(__ushort_as_half(u));
}

__device__ __forceinline__ int cap4(int c) { return (c + 3) & ~3; }

// ---- prep: W swizzle (0..23) + gate/cursor2-init (24) + edge convert (25..)
// Layer 0 fragments: bf16 hi/lo split. Layers 1/2: fp16 hi/lo split.
// NO histogram (degrees recomputed in place1 from staged edges).
__global__ __launch_bounds__(256) void prep_kernel(
    const int* __restrict__ w, int* __restrict__ src32,
    int* __restrict__ dst32, int E,
    const float* __restrict__ W0, const float* __restrict__ W1,
    const float* __restrict__ W2, short8* __restrict__ Wf_hi,
    short8* __restrict__ Wf_lo,
    const float* __restrict__ t, const float* __restrict__ Wg1,
    const float* __restrict__ bg1, const float* __restrict__ Wg2,
    const float* __restrict__ bg2, float* __restrict__ gate,
    int* __restrict__ cursor2, int B)
{
    int b = blockIdx.x;
    if (b < 24) {
        int f = b * 256 + threadIdx.x;   // 0..6143
        int layer = f >> 11;
        int fi = f & 2047;
        int lane = fi & 63;
        int tt = fi >> 6;                // kc*8 + n
        int kc = tt >> 3, n = tt & 7;
        const float* W = (layer == 0) ? W0 : (layer == 1) ? W1 : W2;
        int krow = kc * 32 + (lane >> 4) * 8;
        int col = n * 16 + (lane & 15);
        short8 hv, lv;
        if (layer == 0) {
            #pragma unroll
            for (int j = 0; j < 8; j++) {
                float x = W[(size_t)(krow + j) * D + col];
                unsigned hb = bf16_rne(x);
                float hf = __uint_as_float(hb << 16);
                unsigned lb = bf16_rne(x - hf);
                hv[j] = (short)hb;
                lv[j] = (short)lb;
            }
        } else {
            #pragma unroll
            for (int j = 0; j < 8; j++) {
                float x = W[(size_t)(krow + j) * D + col];
                __half hh = __float2half(x);
                float hf = __half2float(hh);
                __half ll = __float2half(x - hf);
                hv[j] = (short)__half_as_ushort(hh);
                lv[j] = (short)__half_as_ushort(ll);
            }
        }
        Wf_hi[f] = hv;
        Wf_lo[f] = lv;
        return;
    }
    if (b == 24) {
        // staging cursors: fixed slots, no scan needed
        for (int i = threadIdx.x; i < B; i += 256) cursor2[i] = i * SCAP;
        __shared__ float u[D];
        int j = threadIdx.x;
        if (j < D) {
            float tv = t[0];
            u[j] = tanhf(tv * Wg1[j] + bg1[j]);
        }
        __syncthreads();
        if (j < D) {
            float s = bg2[j];
            #pragma unroll 8
            for (int k = 0; k < D; k++) s += u[k] * Wg2[k * D + j];
            gate[j] = 1.0f / (1.0f + expf(-s));
        }
        return;
    }
    // ---- edge convert (int64 auto-detect), pure streaming ----
    __shared__ int flag;
    if (threadIdx.x == 0) {
        int z = 0;
        for (int k = 0; k < 64; k++) z |= w[2 * k + 1];
        flag = (z == 0) ? 1 : 0;   // all odd words zero => int64 layout
    }
    __syncthreads();
    int i64 = flag;
    int e = (b - 25) * 256 + threadIdx.x;
    if (e >= E) return;
    int s = i64 ? w[2 * e] : w[e];                       // little-endian low word
    int d = i64 ? w[2 * (E + e)] : w[E + e];
    src32[e] = s;
    dst32[e] = d;
}

// ----- pass 1: LDS-binned scatter into fixed bucket staging slots ----------
// Each block: 4096 edges -> LDS histogram over dst>>8 buckets -> one global
// atomicAdd per (block,bin) -> scatter (src,dst) into the bucket's slot.
// Same-block-same-instant writes -> same-XCD L2 merge.
#define P1E 16
__global__ __launch_bounds__(256) void binpass_kernel(
    const int* __restrict__ src32, const int* __restrict__ dst32,
    int* __restrict__ cursor2, int2* __restrict__ stag, int E, int B)
{
    __shared__ int cnt[512];
    __shared__ int base[512];
    int tid = threadIdx.x;
    for (int i = tid; i < B; i += 256) cnt[i] = 0;
    __syncthreads();
    int e0 = blockIdx.x * (P1E * 256) + tid;
    int s[P1E], d[P1E], lp[P1E];
    #pragma unroll
    for (int k = 0; k < P1E; k++) {
        int e = e0 + k * 256;
        if (e < E) {
            s[k] = src32[e];
            d[k] = dst32[e];
            lp[k] = atomicAdd(&cnt[d[k] >> RBITS], 1);
        }
    }
    __syncthreads();
    for (int i = tid; i < B; i += 256)
        base[i] = cnt[i] ? atomicAdd(&cursor2[i], cnt[i]) : 0;
    __syncthreads();
    #pragma unroll
    for (int k = 0; k < P1E; k++) {
        int e = e0 + k * 256;
        if (e < E) {
            int bin = d[k] >> RBITS;
            int idx = base[bin] + lp[k];
            if (idx < (bin + 1) * SCAP)          // overflow guard (never hit
                stag[idx] = make_int2(s[k], d[k]);  // for uniform input)
        }
    }
}

// ----- pass 2a: per-bucket degree count + prefix -> obeg/oend/dinv ---------
__global__ __launch_bounds__(256) void place1_kernel(
    const int2* __restrict__ stag, const int* __restrict__ cursor2,
    int* __restrict__ obeg, int* __restrict__ oend,
    float* __restrict__ dinv, int N)
{
    __shared__ int cnt[RSZ];
    __shared__ int wsum[4], wpre[4];
    int b = blockIdx.x, tid = threadIdx.x;
    int d0 = b * RSZ;
    int nd = (d0 + RSZ < N) ? RSZ : N - d0;
    cnt[tid] = 0;
    __syncthreads();
    int ecount = cursor2[b] - b * SCAP;
    if (ecount > SCAP) ecount = SCAP;
    const int2* sp = stag + (size_t)b * SCAP;
    for (int i = tid; i < ecount; i += 256)
        atomicAdd(&cnt[sp[i].y - d0], 1);
    __syncthreads();
    int c = (tid < nd) ? cnt[tid] : 0;
    int cap = cap4(c);
    int s = cap;
    int lane = tid & 63, wid = tid >> 6;
    #pragma unroll
    for (int off = 1; off < 64; off <<= 1) {
        int n = __shfl_up(s, off);
        if (lane >= off) s += n;
    }
    if (lane == 63) wsum[wid] = s;
    __syncthreads();
    if (tid == 0) {
        int a = 0;
        #pragma unroll
        for (int k = 0; k < 4; k++) { wpre[k] = a; a += wsum[k]; }
    }
    __syncthreads();
    int pre = wpre[wid] + (s - cap);     // exclusive prefix of capacities
    if (tid < nd) {
        int beg = b * RCAP + pre;
        obeg[d0 + tid] = beg;
        oend[d0 + tid] = beg + cap;
        dinv[d0 + tid] = rsqrtf((float)(c + 1));
    }
}

// ----- pass 2b: order region in LDS (zero image -> (0,0) pads), burst write
__global__ __launch_bounds__(256) void place2_kernel(
    const int2* __restrict__ stag, const int* __restrict__ cursor2,
    const int* __restrict__ obeg, const int* __restrict__ oend,
    const float* __restrict__ dinv, int2* __restrict__ edges8, int N)
{
    __shared__ int2 buf[RCAP];
    __shared__ int loff[RSZ];
    __shared__ int lcnt[RSZ];
    int b = blockIdx.x, tid = threadIdx.x;
    int d0 = b * RSZ;
    int nd = (d0 + RSZ < N) ? RSZ : N - d0;
    if (tid < nd) {
        loff[tid] = obeg[d0 + tid] - b * RCAP;
        lcnt[tid] = 0;
    }
    __syncthreads();
    int totalcap = oend[d0 + nd - 1] - b * RCAP;   // broadcast load
    int ecount = cursor2[b] - b * SCAP;
    if (ecount > SCAP) ecount = SCAP;
    const int2* sp = stag + (size_t)b * SCAP;
    int2* out = edges8 + (size_t)b * RCAP;
    if (totalcap <= RCAP) {
        for (int i = tid; i < totalcap; i += 256) buf[i] = make_int2(0, 0);
        __syncthreads();
        for (int i = tid; i < ecount; i += 256) {
            int2 sd = sp[i];
            int ld = sd.y - d0;
            int pos = loff[ld] + atomicAdd(&lcnt[ld], 1);
            buf[pos] = make_int2(sd.x, __float_as_int(dinv[sd.x]));
        }
        __syncthreads();
        for (int i = tid; i < totalcap; i += 256) out[i] = buf[i];
    } else {
        // fallback (degenerate degree distribution): direct global
        for (int i = tid; i < totalcap && i < RCAP; i += 256)
            out[i] = make_int2(0, 0);
        __syncthreads();
        for (int i = tid; i < ecount; i += 256) {
            int2 sd = sp[i];
            int ld = sd.y - d0;
            int pos = loff[ld] + atomicAdd(&lcnt[ld], 1);
            if (pos < RCAP)
                out[pos] = make_int2(sd.x, __float_as_int(dinv[sd.x]));
        }
    }
}

// ----- cooperative Wf stage: 16KB (hi 8KB + lo 8KB) per kc into LDS --------
#define WSTAGE(kc_)                                                           \
    {                                                                         \
        short* wb_ = Wfs + (((kc_) & 1) ? 8192 : 0);                          \
        const short8* gh_ = Wf_hi + (size_t)(kc_) * 512;                      \
        const short8* gl_ = Wf_lo + (size_t)(kc_) * 512;                      \
        _Pragma("unroll")                                                     \
        for (int i_ = 0; i_ < 2; i_++) {                                      \
            int c_ = i_ * 256 + w * 64;                                       \
            gload_lds16(gh_ + c_ + lane, wb_ + c_ * 8);                       \
            gload_lds16(gl_ + c_ + lane, wb_ + 4096 + c_ * 8);                \
        }                                                                     \
    }

// ------------- bf16 split MFMA inner block (layer 0) -----------------------
#define MFMA_BLOCK(kc)                                                        \
    {                                                                         \
        const short* wb = Wfs + (((kc) & 1) ? 8192 : 0);                      \
        _Pragma("unroll")                                                     \
        for (int n = 0; n < 8; n++) {                                         \
            short8 bh = *(const short8*)(wb + (n * 64 + lane) * 8);           \
            short8 bl = *(const short8*)(wb + 4096 + (n * 64 + lane) * 8);    \
            acc[0][n] = __builtin_amdgcn_mfma_f32_16x16x32_bf16(ah0, bh, acc[0][n], 0, 0, 0); \
            acc[0][n] = __builtin_amdgcn_mfma_f32_16x16x32_bf16(ah0, bl, acc[0][n], 0, 0, 0); \
            acc[0][n] = __builtin_amdgcn_mfma_f32_16x16x32_bf16(al0, bh, acc[0][n], 0, 0, 0); \
            acc[1][n] = __builtin_amdgcn_mfma_f32_16x16x32_bf16(ah1, bh, acc[1][n], 0, 0, 0); \
            acc[1][n] = __builtin_amdgcn_mfma_f32_16x16x32_bf16(ah1, bl, acc[1][n], 0, 0, 0); \
            acc[1][n] = __builtin_amdgcn_mfma_f32_16x16x32_bf16(al1, bh, acc[1][n], 0, 0, 0); \
        }                                                                     \
    }

// ------------- fp16 split-W MFMA inner block (layers 1/2) ------------------
#define MFMA_BLOCK_F16(kc)                                                    \
    {                                                                         \
        const short* wb = Wfs + (((kc) & 1) ? 8192 : 0);                      \
        _Pragma("unroll")                                                     \
        for (int n = 0; n < 8; n++) {                                         \
            half8 bh = *(const half8*)(wb + (n * 64 + lane) * 8);             \
            half8 bl = *(const half8*)(wb + 4096 + (n * 64 + lane) * 8);      \
            acc[0][n] = __builtin_amdgcn_mfma_f32_16x16x32_f16(ah0, bh, acc[0][n], 0, 0, 0); \
            acc[0][n] = __builtin_amdgcn_mfma_f32_16x16x32_f16(ah0, bl, acc[0][n], 0, 0, 0); \
            acc[1][n] = __builtin_amdgcn_mfma_f32_16x16x32_f16(ah1, bh, acc[1][n], 0, 0, 0); \
            acc[1][n] = __builtin_amdgcn_mfma_f32_16x16x32_f16(ah1, bl, acc[1][n], 0, 0, 0); \
        }                                                                     \
    }

#define EPILOGUE()                                                            \
    _Pragma("unroll")                                                         \
    for (int rt = 0; rt < 2; rt++) {                                          \
        _Pragma("unroll")                                                     \
        for (int reg = 0; reg < 4; reg++) {                                   \
            int row = rowbase + rt * 16 + qd * 4 + reg;                       \
            if (row < M) {                                                    \
                unsigned short* hp = H16 + (size_t)row * D + m16;             \
                _Pragma("unroll")                                             \
                for (int n = 0; n < 8; n++)                                   \
                    hp[n * 16] = __half_as_ushort(__float2half(acc[rt][n][reg])); \
            }                                                                 \
        }                                                                     \
    }

// ------------- GEMM variant A: fp32 X input (layer 0 only) -----------------
#define GBM 128
__device__ __forceinline__ void cvt8(const float* f, short8& hi, short8& lo) {
    #pragma unroll
    for (int j = 0; j < 8; j++) {
        unsigned hb = bf16_rne(f[j]);
        float hf = __uint_as_float(hb << 16);
        unsigned lb = bf16_rne(f[j] - hf);
        hi[j] = (short)hb;
        lo[j] = (short)lb;
    }
}

__global__ __launch_bounds__(256) void gemm_f32_kernel(
    const float* __restrict__ X, const short8* __restrict__ Wf_hi,
    const short8* __restrict__ Wf_lo, unsigned short* __restrict__ H16, int M)
{
    __shared__ short Wfs[16384];   // 32KB: 2 bufs x (hi 8KB + lo 8KB)
    int tid = threadIdx.x;
    int w = tid >> 6, lane = tid & 63;
    int m16 = lane & 15, qd = lane >> 4;
    int rowbase = blockIdx.x * GBM + w * 32;

    int r0 = rowbase + m16;      if (r0 >= M) r0 = M - 1;
    int r1 = rowbase + m16 + 16; if (r1 >= M) r1 = M - 1;
    const float* xp0 = X + (size_t)r0 * D + qd * 8;
    const float* xp1 = X + (size_t)r1 * D + qd * 8;

    floatx4 acc[2][8];
    #pragma unroll
    for (int rt = 0; rt < 2; rt++)
        #pragma unroll
        for (int n = 0; n < 8; n++)
            acc[rt][n] = (floatx4)(0.f);

    #define LOADA(kc_, A0, A1)                                              \
        {                                                                   \
            *(float4*)(A0)     = *(const float4*)(xp0 + (kc_) * 32);        \
            *(float4*)(A0 + 4) = *(const float4*)(xp0 + (kc_) * 32 + 4);    \
            *(float4*)(A1)     = *(const float4*)(xp1 + (kc_) * 32);        \
            *(float4*)(A1 + 4) = *(const float4*)(xp1 + (kc_) * 32 + 4);    \
        }

    float a0c[8], a1c[8], a0n[8], a1n[8];
    WSTAGE(0)
    LOADA(0, a0c, a1c)

    #pragma unroll
    for (int kc = 0; kc < 4; kc++) {
        __syncthreads();     // drains vmcnt: Wf(kc) in LDS, A(kc) in regs
        if (kc < 3) {
            WSTAGE(kc + 1)
            LOADA(kc + 1, a0n, a1n)
        }
        short8 ah0, al0, ah1, al1;
        cvt8(a0c, ah0, al0);
        cvt8(a1c, ah1, al1);
        MFMA_BLOCK(kc)
        if (kc < 3) {
            #pragma unroll
            for (int z = 0; z < 8; z++) { a0c[z] = a0n[z]; a1c[z] = a1n[z]; }
        }
    }
    #undef LOADA
    EPILOGUE()
}

// ------ GEMM variant B: fp16 single-plane X input (layers 1,2) -------------
__global__ __launch_bounds__(256) void gemm_f16_kernel(
    const unsigned short* __restrict__ Xh,
    const short8* __restrict__ Wf_hi, const short8* __restrict__ Wf_lo,
    unsigned short* __restrict__ H16, int M)
{
    __shared__ short Wfs[16384];   // 32KB: 2 bufs x (hi 8KB + lo 8KB)
    int tid = threadIdx.x;
    int w = tid >> 6, lane = tid & 63;
    int m16 = lane & 15, qd = lane >> 4;
    int rowbase = blockIdx.x * GBM + w * 32;

    int r0 = rowbase + m16;      if (r0 >= M) r0 = M - 1;
    int r1 = rowbase + m16 + 16; if (r1 >= M) r1 = M - 1;
    const unsigned short* xh0 = Xh + (size_t)r0 * D + qd * 8;
    const unsigned short* xh1 = Xh + (size_t)r1 * D + qd * 8;

    floatx4 acc[2][8];
    #pragma unroll
    for (int rt = 0; rt < 2; rt++)
        #pragma unroll
        for (int n = 0; n < 8; n++)
            acc[rt][n] = (floatx4)(0.f);

    half8 ah0, ah1, nh0, nh1;
    WSTAGE(0)
    ah0 = *(const half8*)(xh0);
    ah1 = *(const half8*)(xh1);

    #pragma unroll
    for (int kc = 0; kc < 4; kc++) {
        __syncthreads();     // drains vmcnt: Wf(kc) in LDS, A(kc) in regs
        if (kc < 3) {
            WSTAGE(kc + 1)
            nh0 = *(const half8*)(xh0 + (kc + 1) * 32);
            nh1 = *(const half8*)(xh1 + (kc + 1) * 32);
        }
        MFMA_BLOCK_F16(kc)
        if (kc < 3) { ah0 = nh0; ah1 = nh1; }
    }
    EPILOGUE()
}

// ------- per-node aggregation: half-wave/node, 2-round software pipeline ---
// cap4 regions (pads (0,0.0f) => zero-norm, no masking). Meta prefetched two
// rounds ahead; round r+1's gathers issue before round r's FMAs consume.
__global__ __launch_bounds__(256) void agg_kernel(
    const unsigned short* __restrict__ H16, const int2* __restrict__ edges,
    const int* __restrict__ obeg, const int* __restrict__ oend,
    const float* __restrict__ dinv,
    const float* __restrict__ bias, const float* __restrict__ gate,
    float* __restrict__ outF, unsigned short* __restrict__ outH,
    int M, int writeF32)
{
    int t = threadIdx.x;
    int hw = t >> 5;                  // half-wave 0..7
    int l32 = t & 31;
    int node = blockIdx.x * 8 + hw;
    if (node >= M) return;

    int beg = obeg[node];
    int end = oend[node];
    float dv = dinv[node];
    const unsigned short* __restrict__ Hc = H16 + l32 * 4;
    // self row: issue load early, consume after the gather loop
    ushort4 us = *(const ushort4*)(Hc + (size_t)node * D);
    float4 acc = make_float4(0.f, 0.f, 0.f, 0.f);

    if (beg < end) {
        // round-0 meta + gathers (in flight)
        int4 p0 = *(const int4*)(edges + beg);       // (s0,f0,s1,f1)
        int4 p1 = *(const int4*)(edges + beg + 2);   // (s2,f2,s3,f3)
        ushort4 u0 = *(const ushort4*)(Hc + (size_t)p0.x * D);
        ushort4 u1 = *(const ushort4*)(Hc + (size_t)p0.z * D);
        ushort4 u2 = *(const ushort4*)(Hc + (size_t)p1.x * D);
        ushort4 u3 = *(const ushort4*)(Hc + (size_t)p1.z * D);
        // round-1 meta
        int j1 = (beg + 4 < end) ? beg + 4 : beg;    // clamped: always valid
        int4 q0 = *(const int4*)(edges + j1);
        int4 q1 = *(const int4*)(edges + j1 + 2);

        for (int j = beg; j < end; j += 4) {
            // meta two rounds ahead (clamped)
            int jn = j + 8;
            int jp = (jn < end) ? jn : beg;
            int4 r0 = *(const int4*)(edges + jp);
            int4 r1 = *(const int4*)(edges + jp + 2);
            // ISSUE next round's gathers before consuming this round
            ushort4 v0 = *(const ushort4*)(Hc + (size_t)q0.x * D);
            ushort4 v1 = *(const ushort4*)(Hc + (size_t)q0.z * D);
            ushort4 v2 = *(const ushort4*)(Hc + (size_t)q1.x * D);
            ushort4 v3 = *(const ushort4*)(Hc + (size_t)q1.z * D);
            // consume round r
            float n0 = __int_as_float(p0.y) * dv, n1 = __int_as_float(p0.w) * dv;
            float n2 = __int_as_float(p1.y) * dv, n3 = __int_as_float(p1.w) * dv;
            acc.x = fmaf(h2f(u3.x), n3, fmaf(h2f(u2.x), n2, fmaf(h2f(u1.x), n1, fmaf(h2f(u0.x), n0, acc.x))));
            acc.y = fmaf(h2f(u3.y), n3, fmaf(h2f(u2.y), n2, fmaf(h2f(u1.y), n1, fmaf(h2f(u0.y), n0, acc.y))));
            acc.z = fmaf(h2f(u3.z), n3, fmaf(h2f(u2.z), n2, fmaf(h2f(u1.z), n1, fmaf(h2f(u0.z), n0, acc.z))));
            acc.w = fmaf(h2f(u3.w), n3, fmaf(h2f(u2.w), n2, fmaf(h2f(u1.w), n1, fmaf(h2f(u0.w), n0, acc.w))));
            // shift pipeline
            p0 = q0; p1 = q1; q0 = r0; q1 = r1;
            u0 = v0; u1 = v1; u2 = v2; u3 = v3;
        }
    }

    // self-loop term: norm = dinv^2 = 1/deg (exact, matches reference)
    float nself = dv * dv;
    acc.x = fmaf(h2f(us.x), nself, acc.x);
    acc.y = fmaf(h2f(us.y), nself, acc.y);
    acc.z = fmaf(h2f(us.z), nself, acc.z);
    acc.w = fmaf(h2f(us.w), nself, acc.w);

    float4 bv = *(const float4*)(bias + l32 * 4);
    float4 gv = *(const float4*)(gate + l32 * 4);
    acc.x = fmaxf(acc.x + bv.x, 0.f) * gv.x;
    acc.y = fmaxf(acc.y + bv.y, 0.f) * gv.y;
    acc.z = fmaxf(acc.z + bv.z, 0.f) * gv.z;
    acc.w = fmaxf(acc.w + bv.w, 0.f) * gv.w;

    if (writeF32) {
        *(float4*)(outF + (size_t)node * D + l32 * 4) = acc;
    } else {
        ushort4 hs = make_ushort4(
            __half_as_ushort(__float2half(acc.x)),
            __half_as_ushort(__float2half(acc.y)),
            __half_as_ushort(__float2half(acc.z)),
            __half_as_ushort(__float2half(acc.w)));
        *(ushort4*)(outH + (size_t)node * D + l32 * 4) = hs;
    }
}

// ---------------------------------------------------------------------------
static inline size_t align_up(size_t v, size_t a) { return (v + a - 1) & ~(a - 1); }

extern "C" void kernel_launch(void* const* d_in, const int* in_sizes, int n_in,
                              void* d_out, int out_size, void* d_ws, size_t ws_size,
                              hipStream_t stream)
{
    const float* x   = (const float*)d_in[0];
    const int*   ei  = (const int*)d_in[1];   // int32 or int64 (auto-detected)
    const float* ts  = (const float*)d_in[2];
    const float* Wl[3] = { (const float*)d_in[3], (const float*)d_in[5], (const float*)d_in[7] };
    const float* bl[3] = { (const float*)d_in[4], (const float*)d_in[6], (const float*)d_in[8] };
    const float* Wg1 = (const float*)d_in[9];
    const float* bg1 = (const float*)d_in[10];
    const float* Wg2 = (const float*)d_in[11];
    const float* bg2 = (const float*)d_in[12];

    const int N = in_sizes[0] / D;      // 100000
    const int E = in_sizes[1] / 2;      // 600000
    const int B = (N + RSZ - 1) / RSZ;  // coarse buckets (391)

    // workspace carve (all 256B aligned)
    char* p = (char*)d_ws;
    unsigned short* h16 = (unsigned short*)p; p += align_up((size_t)N * D * 2, 256);
    unsigned short* xh  = (unsigned short*)p; p += align_up((size_t)N * D * 2, 256);
    int* src32  = (int*)p;   p += align_up((size_t)E * 4, 256);
    int* dst32  = (int*)p;   p += align_up((size_t)E * 4, 256);
    float* dinv = (float*)p; p += align_up((size_t)N * 4, 256);
    int* obeg   = (int*)p;   p += align_up((size_t)N * 4, 256);
    int* oend   = (int*)p;   p += align_up((size_t)N * 4, 256);
    int* cursor2 = (int*)p;  p += align_up((size_t)B * 4, 256);
    int2* stag  = (int2*)p;  p += align_up((size_t)B * SCAP * 8, 256);
    int2* edges8 = (int2*)p; p += align_up((size_t)B * RCAP * 8, 256);
    float* gate = (float*)p; p += align_up((size_t)D * 4, 256);
    short8* Wf_hi = (short8*)p; p += align_up((size_t)3 * 2048 * 16, 256);
    short8* Wf_lo = (short8*)p; p += align_up((size_t)3 * 2048 * 16, 256);
    (void)ws_size; (void)n_in; (void)out_size;

    int egrid = (E + 255) / 256;
    prep_kernel<<<25 + egrid, 256, 0, stream>>>(
        ei, src32, dst32, E,
        Wl[0], Wl[1], Wl[2], Wf_hi, Wf_lo,
        ts, Wg1, bg1, Wg2, bg2, gate, cursor2, B);
    int g1 = (E + P1E * 256 - 1) / (P1E * 256);
    binpass_kernel<<<g1, 256, 0, stream>>>(src32, dst32, cursor2, stag, E, B);
    place1_kernel<<<B, 256, 0, stream>>>(stag, cursor2, obeg, oend, dinv, N);
    place2_kernel<<<B, 256, 0, stream>>>(stag, cursor2, obeg, oend, dinv, edges8, N);

    int ggrid = (N + GBM - 1) / GBM;
    int agrid = (N + 7) / 8;
    // layer 0: fp32 input, bf16-split path
    gemm_f32_kernel<<<ggrid, 256, 0, stream>>>(x, Wf_hi, Wf_lo, h16, N);
    agg_kernel<<<agrid, 256, 0, stream>>>(h16, edges8, obeg, oend, dinv, bl[0], gate,
                                          nullptr, xh, N, 0);
    // layer 1: fp16 single-plane input, fp16 split-W MFMA
    gemm_f16_kernel<<<ggrid, 256, 0, stream>>>(xh, Wf_hi + 2048, Wf_lo + 2048, h16, N);
    agg_kernel<<<agrid, 256, 0, stream>>>(h16, edges8, obeg, oend, dinv, bl[1], gate,
                                          nullptr, xh, N, 0);
    // layer 2: fp16 single-plane input, fp32 output
    gemm_f16_kernel<<<ggrid, 256, 0, stream>>>(xh, Wf_hi + 4096, Wf_lo + 4096, h16, N);
    agg_kernel<<<agrid, 256, 0, stream>>>(h16, edges8, obeg, oend, dinv, bl[2], gate,
                                          (float*)d_out, nullptr, N, 1);
}